// Round 1
// 1208.934 us; speedup vs baseline: 2.3742x; 2.3742x over previous
//
#include <hip/hip_runtime.h>
#include <math.h>

// CoAttentionFusion — bf16 MFMA rewrite.
// B=8, Sv=1024, St=512, Vd=1024, Td=768, E=512, H=8, D=64.
// All GEMMs: v_mfma_f32_16x16x32_bf16, fp32 accumulate, fp32 epilogues.
// LN / softmax / bias / gate / residual math stays fp32.

typedef __attribute__((ext_vector_type(8))) short s16x8;     // 8 bf16 (4 VGPR)
typedef __attribute__((ext_vector_type(4))) float f32x4;     // MFMA acc
typedef __attribute__((ext_vector_type(4))) unsigned short us4;

__device__ __forceinline__ float gelu_exact(float x) {
  return 0.5f * x * (1.0f + erff(x * 0.70710678118654752f));
}
__device__ __forceinline__ float sigmoidf_(float x) {
  return 1.0f / (1.0f + expf(-x));
}
__device__ __forceinline__ unsigned short f2bf(float f) {
  unsigned int u = __float_as_uint(f);
  u += 0x7fffu + ((u >> 16) & 1u);  // RNE
  return (unsigned short)(u >> 16);
}

// ---------------- LayerNorm: fp32 in -> bf16 out (optional exact GELU) -----
template <bool GELU>
__global__ __launch_bounds__(256) void ln_kernel(
    const float* __restrict__ x, const float* __restrict__ g,
    const float* __restrict__ b, unsigned short* __restrict__ out, int cols) {
  const int row = blockIdx.x;
  const float2* xr = (const float2*)(x + (size_t)row * cols);
  const float2* g2 = (const float2*)g;
  const float2* b2 = (const float2*)b;
  const int n2 = cols >> 1;
  const int tid = threadIdx.x;
  float s = 0.f, ss = 0.f;
  for (int c = tid; c < n2; c += 256) {
    float2 v = xr[c];
    s += v.x + v.y;
    ss += v.x * v.x + v.y * v.y;
  }
#pragma unroll
  for (int off = 32; off; off >>= 1) {
    s += __shfl_down(s, off, 64);
    ss += __shfl_down(ss, off, 64);
  }
  __shared__ float rs[4], rss[4], stat[2];
  const int lane = tid & 63, wid = tid >> 6;
  if (lane == 0) {
    rs[wid] = s;
    rss[wid] = ss;
  }
  __syncthreads();
  if (tid == 0) {
    float ts = rs[0] + rs[1] + rs[2] + rs[3];
    float tss = rss[0] + rss[1] + rss[2] + rss[3];
    float m = ts / (float)cols;
    float var = tss / (float)cols - m * m;
    stat[0] = m;
    stat[1] = 1.0f / sqrtf(var + 1e-5f);
  }
  __syncthreads();
  const float m = stat[0], inv = stat[1];
  ushort2* o2 = (ushort2*)(out + (size_t)row * cols);
  for (int c = tid; c < n2; c += 256) {
    float2 v = xr[c];
    float2 gg = g2[c], bb = b2[c];
    float o0 = (v.x - m) * inv * gg.x + bb.x;
    float o1 = (v.y - m) * inv * gg.y + bb.y;
    if (GELU) {
      o0 = gelu_exact(o0);
      o1 = gelu_exact(o1);
    }
    ushort2 r;
    r.x = f2bf(o0);
    r.y = f2bf(o1);
    o2[c] = r;
  }
}

// ---------------- row softmax: fp32 in-place + bf16 copy -------------------
template <int NIT>  // row length = NIT*512 floats
__global__ __launch_bounds__(256) void softmax_kernel(
    float* __restrict__ p, unsigned short* __restrict__ pb) {
  const size_t base = (size_t)blockIdx.x * (NIT * 512);
  float2* pr = (float2*)(p + base);
  ushort2* pb2 = (ushort2*)(pb + base);
  const int tid = threadIdx.x;
  float2 vals[NIT];
  float mx = -1e30f;
#pragma unroll
  for (int i = 0; i < NIT; ++i) {
    vals[i] = pr[tid + i * 256];
    mx = fmaxf(mx, fmaxf(vals[i].x, vals[i].y));
  }
  __shared__ float red[4];
#pragma unroll
  for (int off = 32; off; off >>= 1) mx = fmaxf(mx, __shfl_down(mx, off, 64));
  const int lane = tid & 63, wid = tid >> 6;
  if (lane == 0) red[wid] = mx;
  __syncthreads();
  mx = fmaxf(fmaxf(red[0], red[1]), fmaxf(red[2], red[3]));
  float s = 0.f;
#pragma unroll
  for (int i = 0; i < NIT; ++i) {
    vals[i].x = expf(vals[i].x - mx);
    vals[i].y = expf(vals[i].y - mx);
    s += vals[i].x + vals[i].y;
  }
  __syncthreads();
#pragma unroll
  for (int off = 32; off; off >>= 1) s += __shfl_down(s, off, 64);
  if (lane == 0) red[wid] = s;
  __syncthreads();
  s = red[0] + red[1] + red[2] + red[3];
  const float inv = 1.0f / s;
#pragma unroll
  for (int i = 0; i < NIT; ++i) {
    float2 o;
    o.x = vals[i].x * inv;
    o.y = vals[i].y * inv;
    pr[tid + i * 256] = o;
    ushort2 r;
    r.x = f2bf(o.x);
    r.y = f2bf(o.y);
    pb2[tid + i * 256] = r;
  }
}

// ---------------- flat fp32 -> bf16 cast -----------------------------------
__global__ __launch_bounds__(256) void cast_kernel(
    const float* __restrict__ x, unsigned short* __restrict__ o, int n4) {
  const int stride = gridDim.x * 256;
  for (int i = blockIdx.x * 256 + threadIdx.x; i < n4; i += stride) {
    float4 v = ((const float4*)x)[i];
    us4 r = {f2bf(v.x), f2bf(v.y), f2bf(v.z), f2bf(v.w)};
    ((us4*)o)[i] = r;
  }
}

// ---------------- transpose-cast: fp32 [R,C] -> bf16 [C,R], up to 8 mats ---
struct TP {
  const float* s[8];
  unsigned short* d[8];
};
__global__ __launch_bounds__(256) void tc_kernel(TP tp, int R, int C) {
  __shared__ unsigned short tile[32][33];
  const float* src = tp.s[blockIdx.z];
  unsigned short* dst = tp.d[blockIdx.z];
  const int r0 = blockIdx.y * 32, c0 = blockIdx.x * 32;
  const int t = threadIdx.x;
  const int tr = t >> 3, tc4 = (t & 7) * 4;
  float4 v = *(const float4*)(src + (size_t)(r0 + tr) * C + c0 + tc4);
  tile[tr][tc4 + 0] = f2bf(v.x);
  tile[tr][tc4 + 1] = f2bf(v.y);
  tile[tr][tc4 + 2] = f2bf(v.z);
  tile[tr][tc4 + 3] = f2bf(v.w);
  __syncthreads();
  us4 o = {tile[tc4 + 0][tr], tile[tc4 + 1][tr], tile[tc4 + 2][tr],
           tile[tc4 + 3][tr]};
  *(us4*)(dst + (size_t)(c0 + tr) * R + r0 + tc4) = o;
}

// ---------------- MFMA GEMM ------------------------------------------------
// C[m,n] = epi( sum_k A[m,k]*Bt[n,k] + bias[n] )
// A, Bt bf16 row-major. BK=32. LDS rows hold the 32 k-values PERMUTED so that
// one ds_read_b128 at byte h*16 (h = lane>>4) yields the mfma operand
// k = {4h..4h+3, 16+4h..16+4h+3}  (two K=16 halves of the x32 op).
// Row stride 40 ushorts (80 B) keeps 16B alignment and spreads banks.
enum { EPI_B = 0, EPI_BG = 1, EPI_BR = 2, EPI_BGATE = 3, EPI_SC = 4 };

template <int ROWS>
__device__ __forceinline__ void stage_tile(unsigned short (*lds)[40],
                                           const unsigned short* __restrict__ g,
                                           size_t ld) {
  const int t = threadIdx.x;
  const int jr = t & 3;  // 16B chunk within row: k = 8*jr..8*jr+7
  // permuted LDS byte base for this chunk's first 4 bf16
  const int B0 = (jr < 2) ? (jr * 32) : ((jr - 2) * 32 + 8);
#pragma unroll
  for (int p = 0; p < ROWS / 64; ++p) {
    const int row = (t >> 2) + p * 64;
    uint4 u = *(const uint4*)(g + (size_t)row * ld + jr * 8);
    char* dst = (char*)(&lds[row][0]) + B0;
    *(unsigned long long*)dst = ((const unsigned long long*)&u)[0];
    *(unsigned long long*)(dst + 16) = ((const unsigned long long*)&u)[1];
  }
}

template <int EPI, int OM, int BN, bool CONCAT>
__global__ __launch_bounds__(256) void mm(
    const unsigned short* __restrict__ A0,
    const unsigned short* __restrict__ A1, int lda0, int lda1, int K0, int K,
    const unsigned short* __restrict__ Bt, int ldb,
    const float* __restrict__ bias, const float* __restrict__ X1,
    const float* __restrict__ X2, float* __restrict__ outF,
    unsigned short* __restrict__ outB, int ldc, float scale, size_t aZb,
    size_t aZh, size_t bZb, size_t bZh, size_t cZb, size_t cZh) {
  constexpr int WN = BN / 2;   // wave n-extent (64 or 32)
  constexpr int NJ = WN / 16;  // n-fragments per wave (4 or 2)
  __shared__ unsigned short As[128][40];
  __shared__ unsigned short Bs[BN][40];
  const int z = blockIdx.z;
  const size_t zb = z >> 3, zh = z & 7;
  const int m0 = blockIdx.y * 128, n0 = blockIdx.x * BN;
  const int t = threadIdx.x;
  const int w = t >> 6, lane = t & 63;
  const int h = lane >> 4, r16 = lane & 15;
  const int wm = w >> 1, wn = w & 1;
  const unsigned short* Ab = A0 + zb * aZb + zh * aZh + (size_t)m0 * lda0;
  const unsigned short* A1b = CONCAT ? (A1 + (size_t)m0 * lda1) : nullptr;
  const unsigned short* Bb = Bt + zb * bZb + zh * bZh + (size_t)n0 * ldb;
  f32x4 acc[4][NJ] = {};
  for (int k0 = 0; k0 < K; k0 += 32) {
    const unsigned short* ag;
    size_t lda;
    if (CONCAT && k0 >= K0) {
      ag = A1b + (k0 - K0);
      lda = (size_t)lda1;
    } else {
      ag = Ab + k0;
      lda = (size_t)lda0;
    }
    stage_tile<128>(As, ag, lda);
    stage_tile<BN>(Bs, Bb + k0, (size_t)ldb);
    __syncthreads();
    const unsigned short* ap = &As[wm * 64 + r16][h * 8];
    const unsigned short* bp = &Bs[wn * WN + r16][h * 8];
    s16x8 av[4], bv[NJ];
#pragma unroll
    for (int i = 0; i < 4; ++i) av[i] = *(const s16x8*)(ap + i * 640);
#pragma unroll
    for (int j = 0; j < NJ; ++j) bv[j] = *(const s16x8*)(bp + j * 640);
#pragma unroll
    for (int i = 0; i < 4; ++i)
#pragma unroll
      for (int j = 0; j < NJ; ++j)
        acc[i][j] = __builtin_amdgcn_mfma_f32_16x16x32_bf16(av[i], bv[j],
                                                            acc[i][j], 0, 0, 0);
    __syncthreads();
  }
  // epilogue: C frag layout col=lane&15, row=4*(lane>>4)+reg  [measured]
  const size_t cz = zb * cZb + zh * cZh;
#pragma unroll
  for (int i = 0; i < 4; ++i) {
    const int rr = m0 + wm * 64 + i * 16 + h * 4;
#pragma unroll
    for (int j = 0; j < NJ; ++j) {
      const int cc = n0 + wn * WN + j * 16 + r16;
      const float bb = (EPI == EPI_SC) ? 0.f : bias[cc];
#pragma unroll
      for (int q = 0; q < 4; ++q) {
        float v = acc[i][j][q];
        v = (EPI == EPI_SC) ? v * scale : v + bb;
        if (EPI == EPI_BG) v = gelu_exact(v);
        const size_t idx = cz + (size_t)(rr + q) * ldc + cc;
        if (EPI == EPI_BR) v = X1[idx] + v;
        if (EPI == EPI_BGATE) v = X1[idx] + sigmoidf_(v) * X2[idx];
        if (OM & 1) outF[idx] = v;
        if (OM & 2) outB[idx] = f2bf(v);
      }
    }
  }
}

extern "C" void kernel_launch(void* const* d_in, const int* in_sizes, int n_in,
                              void* d_out, int out_size, void* d_ws,
                              size_t ws_size, hipStream_t stream) {
  (void)in_sizes;
  (void)n_in;
  (void)out_size;
  (void)ws_size;
  const int B = 8, Sv = 1024, St = 512, Vd = 1024, Td = 768, E = 512;
  auto inf = [&](int i) { return (const float*)d_in[i]; };
  float* out = (float*)d_out;
  char* ws = (char*)d_ws;
  float* out_vis = out;             // [8192,512]
  float* out_txt = out + 4194304;   // [4096,512]
  float* w_t2v = out + 6291456;     // [8,8,512,1024]
  float* w_v2t = out + 39845888;    // [8,8,1024,512]

  // workspace arena (bytes); peak 114.8 MB (previous kernel used 117.4 MB)
  const size_t BIGo = 0;                    // 64 MiB multi-use
  const size_t R1o = 67108864;              // 16 MiB
  const size_t R2o = R1o + 16777216;        // 16 MiB
  const size_t R3o = R2o + 16777216;        // weights (5.77 MB attn / 8.39 FF)
  const size_t R4o = R3o + 5767168;         // vt (8.39 MB)
  auto U = [&](size_t o) { return (unsigned short*)(ws + o); };
  auto F = [&](size_t o) { return (float*)(ws + o); };

  // ===================== t2v: text queries attend to vision ================
  {
    const int pb = 2;
    const int Sq = St, Sk = Sv, Mq = B * Sq, Mk = B * Sk;  // 512,1024,4096,8192
    unsigned short* wq_t = U(R3o + 0);        // [512][768]
    unsigned short* wk_t = U(R3o + 786432);   // [512][1024]
    unsigned short* wv_t = U(R3o + 1835008);  // [512][1024]
    unsigned short* wo_t = U(R3o + 2883584);  // [512][512]
    unsigned short* wgp_t = U(R3o + 3407872); // [512][768]
    unsigned short* g1w_t = U(R3o + 4194304); // [512][1024]
    unsigned short* g2w_t = U(R3o + 5242880); // [512][512]
    {
      TP tp{};
      tp.s[0] = inf(pb + 4); tp.d[0] = wq_t;
      tp.s[1] = inf(pb + 12); tp.d[1] = wgp_t;
      tc_kernel<<<dim3(16, 24, 2), 256, 0, stream>>>(tp, 768, 512);
    }
    {
      TP tp{};
      tp.s[0] = inf(pb + 6); tp.d[0] = wk_t;
      tp.s[1] = inf(pb + 8); tp.d[1] = wv_t;
      tp.s[2] = inf(pb + 14); tp.d[2] = g1w_t;
      tc_kernel<<<dim3(16, 32, 3), 256, 0, stream>>>(tp, 1024, 512);
    }
    {
      TP tp{};
      tp.s[0] = inf(pb + 10); tp.d[0] = wo_t;
      tp.s[1] = inf(pb + 18); tp.d[1] = g2w_t;
      tc_kernel<<<dim3(16, 16, 2), 256, 0, stream>>>(tp, 512, 512);
    }
    unsigned short* qn = U(BIGo);                 // [4096,768]
    unsigned short* kn = U(R1o);                  // [8192,1024]
    unsigned short* q_bf = U(BIGo + 16777216);    // [4096,512]
    unsigned short* k_bf = U(BIGo + 25165824);    // [8192,512]
    float* v_f = F(R2o);                          // [8192,512] fp32
    unsigned short* w_bf = U(BIGo);               // [64,512,1024]
    unsigned short* vt = U(R4o);                  // [8,512,1024]
    unsigned short* ctx_bf = U(R1o);              // [4096,512]
    float* att_f = F(R2o);                        // [4096,512]
    unsigned short* att_bf = U(BIGo + 50331648);
    unsigned short* txt_bf = U(BIGo);             // [4096,768]
    float* qp_f = F(R1o + 8388608);               // [4096,512]
    unsigned short* qp_bf = U(BIGo + 58720256);
    float* h_f = F(BIGo + 16777216);              // [4096,512]
    unsigned short* hg = U(BIGo);                 // [4096,512]

    ln_kernel<false><<<Mq, 256, 0, stream>>>(inf(1), inf(pb + 0), inf(pb + 1),
                                             qn, Td);
    ln_kernel<false><<<Mk, 256, 0, stream>>>(inf(0), inf(pb + 2), inf(pb + 3),
                                             kn, Vd);
    mm<EPI_B, 2, 64, false><<<dim3(8, 32, 1), 256, 0, stream>>>(
        qn, nullptr, Td, 0, Td, Td, wq_t, Td, inf(pb + 5), nullptr, nullptr,
        nullptr, q_bf, E, 1.f, 0, 0, 0, 0, 0, 0);
    mm<EPI_B, 2, 128, false><<<dim3(4, 64, 1), 256, 0, stream>>>(
        kn, nullptr, Vd, 0, Vd, Vd, wk_t, Vd, inf(pb + 7), nullptr, nullptr,
        nullptr, k_bf, E, 1.f, 0, 0, 0, 0, 0, 0);
    mm<EPI_B, 1, 128, false><<<dim3(4, 64, 1), 256, 0, stream>>>(
        kn, nullptr, Vd, 0, Vd, Vd, wv_t, Vd, inf(pb + 9), nullptr, nullptr,
        v_f, nullptr, E, 1.f, 0, 0, 0, 0, 0, 0);
    mm<EPI_SC, 1, 128, false><<<dim3(Sk / 128, Sq / 128, 64), 256, 0, stream>>>(
        q_bf, nullptr, E, 0, 64, 64, k_bf, E, nullptr, nullptr, nullptr,
        w_t2v, nullptr, Sk, 0.125f, (size_t)Sq * E, 64, (size_t)Sk * E, 64,
        (size_t)8 * Sq * Sk, (size_t)Sq * Sk);
    softmax_kernel<2><<<64 * Sq, 256, 0, stream>>>(w_t2v, w_bf);
    {
      TP tp{};
      for (int i = 0; i < 8; ++i) {
        tp.s[i] = v_f + (size_t)i * Sk * E;
        tp.d[i] = vt + (size_t)i * E * Sk;
      }
      tc_kernel<<<dim3(E / 32, Sk / 32, 8), 256, 0, stream>>>(tp, Sk, E);
    }
    mm<EPI_SC, 2, 64, false><<<dim3(1, Sq / 128, 64), 256, 0, stream>>>(
        w_bf, nullptr, Sk, 0, Sk, Sk, vt, Sk, nullptr, nullptr, nullptr,
        nullptr, ctx_bf, E, 1.f, (size_t)8 * Sq * Sk, (size_t)Sq * Sk,
        (size_t)E * Sk, (size_t)64 * Sk, (size_t)Sq * E, 64);
    mm<EPI_B, 3, 64, false><<<dim3(8, 32, 1), 256, 0, stream>>>(
        ctx_bf, nullptr, E, 0, E, E, wo_t, E, inf(pb + 11), nullptr, nullptr,
        att_f, att_bf, E, 1.f, 0, 0, 0, 0, 0, 0);
    cast_kernel<<<1024, 256, 0, stream>>>(inf(1), txt_bf, Mq * Td / 4);
    mm<EPI_B, 3, 64, false><<<dim3(8, 32, 1), 256, 0, stream>>>(
        txt_bf, nullptr, Td, 0, Td, Td, wgp_t, Td, inf(pb + 13), nullptr,
        nullptr, qp_f, qp_bf, E, 1.f, 0, 0, 0, 0, 0, 0);
    mm<EPI_B, 1, 64, true><<<dim3(8, 32, 1), 256, 0, stream>>>(
        qp_bf, att_bf, E, E, E, 2 * E, g1w_t, 2 * E, inf(pb + 15), nullptr,
        nullptr, h_f, nullptr, E, 1.f, 0, 0, 0, 0, 0, 0);
    ln_kernel<true><<<Mq, 256, 0, stream>>>(h_f, inf(pb + 16), inf(pb + 17),
                                            hg, E);
    mm<EPI_BGATE, 1, 64, false><<<dim3(8, 32, 1), 256, 0, stream>>>(
        hg, nullptr, E, 0, E, E, g2w_t, E, inf(pb + 19), qp_f, att_f, out_txt,
        nullptr, E, 1.f, 0, 0, 0, 0, 0, 0);
  }
  // ===================== v2t: vision queries attend to text ================
  {
    const int pb = 22;
    const int Sq = Sv, Sk = St, Mq = B * Sq, Mk = B * Sk;  // 1024,512,8192,4096
    unsigned short* wq_t = U(R3o + 0);        // [512][1024]
    unsigned short* wk_t = U(R3o + 1048576);  // [512][768]
    unsigned short* wv_t = U(R3o + 1835008);  // [512][768]
    unsigned short* wo_t = U(R3o + 2621440);  // [512][512]
    unsigned short* wgp_t = U(R3o + 3145728); // [512][1024]
    unsigned short* g1w_t = U(R3o + 4194304); // [512][1024]
    unsigned short* g2w_t = U(R3o + 5242880); // [512][512]
    {
      TP tp{};
      tp.s[0] = inf(pb + 4); tp.d[0] = wq_t;
      tp.s[1] = inf(pb + 12); tp.d[1] = wgp_t;
      tp.s[2] = inf(pb + 14); tp.d[2] = g1w_t;
      tc_kernel<<<dim3(16, 32, 3), 256, 0, stream>>>(tp, 1024, 512);
    }
    {
      TP tp{};
      tp.s[0] = inf(pb + 6); tp.d[0] = wk_t;
      tp.s[1] = inf(pb + 8); tp.d[1] = wv_t;
      tc_kernel<<<dim3(16, 24, 2), 256, 0, stream>>>(tp, 768, 512);
    }
    {
      TP tp{};
      tp.s[0] = inf(pb + 10); tp.d[0] = wo_t;
      tp.s[1] = inf(pb + 18); tp.d[1] = g2w_t;
      tc_kernel<<<dim3(16, 16, 2), 256, 0, stream>>>(tp, 512, 512);
    }
    unsigned short* qn = U(BIGo);                 // [8192,1024]
    unsigned short* kn = U(R1o);                  // [4096,768]
    unsigned short* q_bf = U(BIGo + 16777216);    // [8192,512]
    unsigned short* k_bf = U(BIGo + 25165824);    // [4096,512]
    float* v_f = F(R2o);                          // [4096,512]
    unsigned short* w_bf = U(BIGo);               // [64,1024,512]
    unsigned short* vt = U(R4o);                  // [8,512,512]
    unsigned short* ctx_bf = U(R1o);              // [8192,512]
    float* att_f = F(R2o);                        // [8192,512]
    unsigned short* att_bf = U(BIGo + 50331648);
    unsigned short* vis_bf = U(BIGo);             // [8192,1024]
    float* qp_f = F(R1o);                         // [8192,512]
    unsigned short* qp_bf = U(BIGo + 58720256);
    float* h_f = F(BIGo + 16777216);              // [8192,512]
    unsigned short* hg = U(BIGo);                 // [8192,512]

    ln_kernel<false><<<Mq, 256, 0, stream>>>(inf(0), inf(pb + 0), inf(pb + 1),
                                             qn, Vd);
    ln_kernel<false><<<Mk, 256, 0, stream>>>(inf(1), inf(pb + 2), inf(pb + 3),
                                             kn, Td);
    mm<EPI_B, 2, 128, false><<<dim3(4, 64, 1), 256, 0, stream>>>(
        qn, nullptr, Vd, 0, Vd, Vd, wq_t, Vd, inf(pb + 5), nullptr, nullptr,
        nullptr, q_bf, E, 1.f, 0, 0, 0, 0, 0, 0);
    mm<EPI_B, 2, 64, false><<<dim3(8, 32, 1), 256, 0, stream>>>(
        kn, nullptr, Td, 0, Td, Td, wk_t, Td, inf(pb + 7), nullptr, nullptr,
        nullptr, k_bf, E, 1.f, 0, 0, 0, 0, 0, 0);
    mm<EPI_B, 1, 64, false><<<dim3(8, 32, 1), 256, 0, stream>>>(
        kn, nullptr, Td, 0, Td, Td, wv_t, Td, inf(pb + 9), nullptr, nullptr,
        v_f, nullptr, E, 1.f, 0, 0, 0, 0, 0, 0);
    mm<EPI_SC, 1, 128, false><<<dim3(Sk / 128, Sq / 128, 64), 256, 0, stream>>>(
        q_bf, nullptr, E, 0, 64, 64, k_bf, E, nullptr, nullptr, nullptr,
        w_v2t, nullptr, Sk, 0.125f, (size_t)Sq * E, 64, (size_t)Sk * E, 64,
        (size_t)8 * Sq * Sk, (size_t)Sq * Sk);
    softmax_kernel<1><<<64 * Sq, 256, 0, stream>>>(w_v2t, w_bf);
    {
      TP tp{};
      for (int i = 0; i < 8; ++i) {
        tp.s[i] = v_f + (size_t)i * Sk * E;
        tp.d[i] = vt + (size_t)i * E * Sk;
      }
      tc_kernel<<<dim3(E / 32, Sk / 32, 8), 256, 0, stream>>>(tp, Sk, E);
    }
    mm<EPI_SC, 2, 64, false><<<dim3(1, Sq / 128, 64), 256, 0, stream>>>(
        w_bf, nullptr, Sk, 0, Sk, Sk, vt, Sk, nullptr, nullptr, nullptr,
        nullptr, ctx_bf, E, 1.f, (size_t)8 * Sq * Sk, (size_t)Sq * Sk,
        (size_t)E * Sk, (size_t)64 * Sk, (size_t)Sq * E, 64);
    mm<EPI_B, 3, 128, false><<<dim3(4, 64, 1), 256, 0, stream>>>(
        ctx_bf, nullptr, E, 0, E, E, wo_t, E, inf(pb + 11), nullptr, nullptr,
        att_f, att_bf, E, 1.f, 0, 0, 0, 0, 0, 0);
    cast_kernel<<<2048, 256, 0, stream>>>(inf(0), vis_bf, Mq * Vd / 4);
    mm<EPI_B, 3, 128, false><<<dim3(4, 64, 1), 256, 0, stream>>>(
        vis_bf, nullptr, Vd, 0, Vd, Vd, wgp_t, Vd, inf(pb + 13), nullptr,
        nullptr, qp_f, qp_bf, E, 1.f, 0, 0, 0, 0, 0, 0);
    mm<EPI_B, 1, 128, true><<<dim3(4, 64, 1), 256, 0, stream>>>(
        qp_bf, att_bf, E, E, E, 2 * E, g1w_t, 2 * E, inf(pb + 15), nullptr,
        nullptr, h_f, nullptr, E, 1.f, 0, 0, 0, 0, 0, 0);
    ln_kernel<true><<<Mq, 256, 0, stream>>>(h_f, inf(pb + 16), inf(pb + 17),
                                            hg, E);
    mm<EPI_BGATE, 1, 128, false><<<dim3(4, 64, 1), 256, 0, stream>>>(
        hg, nullptr, E, 0, E, E, g2w_t, E, inf(pb + 19), qp_f, att_f, out_vis,
        nullptr, E, 1.f, 0, 0, 0, 0, 0, 0);
  }
  // ===================== FF blocks ========================================
  {
    unsigned short* vw1_t = U(R3o + 0);        // [2048][512]
    unsigned short* vw2_t = U(R3o + 2097152);  // [512][2048]
    unsigned short* tw1_t = U(R3o + 4194304);
    unsigned short* tw2_t = U(R3o + 6291456);
    {
      TP tp{};
      tp.s[0] = inf(44); tp.d[0] = vw1_t;
      tp.s[1] = inf(50); tp.d[1] = tw1_t;
      tc_kernel<<<dim3(64, 16, 2), 256, 0, stream>>>(tp, 512, 2048);
    }
    {
      TP tp{};
      tp.s[0] = inf(46); tp.d[0] = vw2_t;
      tp.s[1] = inf(52); tp.d[1] = tw2_t;
      tc_kernel<<<dim3(16, 64, 2), 256, 0, stream>>>(tp, 2048, 512);
    }
    unsigned short* lnv = U(BIGo);
    unsigned short* y_v = U(BIGo + 8388608);   // [8192,2048]
    unsigned short* lnt = U(BIGo + 41943040);
    unsigned short* y_t = U(BIGo + 46137344);  // [4096,2048]
    ln_kernel<false><<<8192, 256, 0, stream>>>(out_vis, inf(42), inf(43), lnv,
                                               512);
    mm<EPI_BG, 2, 128, false><<<dim3(16, 64, 1), 256, 0, stream>>>(
        lnv, nullptr, 512, 0, 512, 512, vw1_t, 512, inf(45), nullptr, nullptr,
        nullptr, y_v, 2048, 1.f, 0, 0, 0, 0, 0, 0);
    mm<EPI_BR, 1, 128, false><<<dim3(4, 64, 1), 256, 0, stream>>>(
        y_v, nullptr, 2048, 0, 2048, 2048, vw2_t, 2048, inf(47), out_vis,
        nullptr, out_vis, nullptr, 512, 1.f, 0, 0, 0, 0, 0, 0);
    ln_kernel<false><<<4096, 256, 0, stream>>>(out_txt, inf(48), inf(49), lnt,
                                               512);
    mm<EPI_BG, 2, 128, false><<<dim3(16, 32, 1), 256, 0, stream>>>(
        lnt, nullptr, 512, 0, 512, 512, tw1_t, 512, inf(51), nullptr, nullptr,
        nullptr, y_t, 2048, 1.f, 0, 0, 0, 0, 0, 0);
    mm<EPI_BR, 1, 64, false><<<dim3(8, 32, 1), 256, 0, stream>>>(
        y_t, nullptr, 2048, 0, 2048, 2048, tw2_t, 2048, inf(53), out_txt,
        nullptr, out_txt, nullptr, 512, 1.f, 0, 0, 0, 0, 0, 0);
  }
}

// Round 3
// 1190.208 us; speedup vs baseline: 2.4116x; 1.0157x over previous
//
#include <hip/hip_runtime.h>
#include <math.h>

// CoAttentionFusion — bf16 MFMA, fused scores+softmax, fused KV projection.
// B=8, Sv=1024, St=512, Vd=1024, Td=768, E=512, H=8, D=64.
// (Round 3 = round 2 resubmit: container failed twice = infra flake; static
//  audit found no OOB/hang. See round-2 analysis.)

typedef __attribute__((ext_vector_type(8))) short s16x8;     // 8 bf16 (4 VGPR)
typedef __attribute__((ext_vector_type(4))) float f32x4;     // MFMA acc
typedef __attribute__((ext_vector_type(4))) unsigned short us4;

__device__ __forceinline__ float gelu_exact(float x) {
  return 0.5f * x * (1.0f + erff(x * 0.70710678118654752f));
}
__device__ __forceinline__ float sigmoidf_(float x) {
  return 1.0f / (1.0f + expf(-x));
}
__device__ __forceinline__ unsigned short f2bf(float f) {
  unsigned int u = __float_as_uint(f);
  u += 0x7fffu + ((u >> 16) & 1u);  // RNE
  return (unsigned short)(u >> 16);
}

// ---------------- LayerNorm: fp32 in -> bf16 out (optional exact GELU) -----
template <bool GELU>
__global__ __launch_bounds__(256) void ln_kernel(
    const float* __restrict__ x, const float* __restrict__ g,
    const float* __restrict__ b, unsigned short* __restrict__ out, int cols) {
  const int row = blockIdx.x;
  const float2* xr = (const float2*)(x + (size_t)row * cols);
  const float2* g2 = (const float2*)g;
  const float2* b2 = (const float2*)b;
  const int n2 = cols >> 1;
  const int tid = threadIdx.x;
  float s = 0.f, ss = 0.f;
  for (int c = tid; c < n2; c += 256) {
    float2 v = xr[c];
    s += v.x + v.y;
    ss += v.x * v.x + v.y * v.y;
  }
#pragma unroll
  for (int off = 32; off; off >>= 1) {
    s += __shfl_down(s, off, 64);
    ss += __shfl_down(ss, off, 64);
  }
  __shared__ float rs[4], rss[4], stat[2];
  const int lane = tid & 63, wid = tid >> 6;
  if (lane == 0) {
    rs[wid] = s;
    rss[wid] = ss;
  }
  __syncthreads();
  if (tid == 0) {
    float ts = rs[0] + rs[1] + rs[2] + rs[3];
    float tss = rss[0] + rss[1] + rss[2] + rss[3];
    float m = ts / (float)cols;
    float var = tss / (float)cols - m * m;
    stat[0] = m;
    stat[1] = 1.0f / sqrtf(var + 1e-5f);
  }
  __syncthreads();
  const float m = stat[0], inv = stat[1];
  ushort2* o2 = (ushort2*)(out + (size_t)row * cols);
  for (int c = tid; c < n2; c += 256) {
    float2 v = xr[c];
    float2 gg = g2[c], bb = b2[c];
    float o0 = (v.x - m) * inv * gg.x + bb.x;
    float o1 = (v.y - m) * inv * gg.y + bb.y;
    if (GELU) {
      o0 = gelu_exact(o0);
      o1 = gelu_exact(o1);
    }
    ushort2 r;
    r.x = f2bf(o0);
    r.y = f2bf(o1);
    o2[c] = r;
  }
}

// ---------------- flat fp32 -> bf16 cast -----------------------------------
__global__ __launch_bounds__(256) void cast_kernel(
    const float* __restrict__ x, unsigned short* __restrict__ o, int n4) {
  const int stride = gridDim.x * 256;
  for (int i = blockIdx.x * 256 + threadIdx.x; i < n4; i += stride) {
    float4 v = ((const float4*)x)[i];
    us4 r = {f2bf(v.x), f2bf(v.y), f2bf(v.z), f2bf(v.w)};
    ((us4*)o)[i] = r;
  }
}

// ---------------- transpose-cast: fp32 [R,C] -> bf16 [C,R], up to 8 mats ---
struct TP {
  const float* s[8];
  unsigned short* d[8];
};
__global__ __launch_bounds__(256) void tc_kernel(TP tp, int R, int C) {
  __shared__ unsigned short tile[32][33];
  const float* src = tp.s[blockIdx.z];
  unsigned short* dst = tp.d[blockIdx.z];
  const int r0 = blockIdx.y * 32, c0 = blockIdx.x * 32;
  const int t = threadIdx.x;
  const int tr = t >> 3, tc4 = (t & 7) * 4;
  float4 v = *(const float4*)(src + (size_t)(r0 + tr) * C + c0 + tc4);
  tile[tr][tc4 + 0] = f2bf(v.x);
  tile[tr][tc4 + 1] = f2bf(v.y);
  tile[tr][tc4 + 2] = f2bf(v.z);
  tile[tr][tc4 + 3] = f2bf(v.w);
  __syncthreads();
  us4 o = {tile[tc4 + 0][tr], tile[tc4 + 1][tr], tile[tc4 + 2][tr],
           tile[tc4 + 3][tr]};
  *(us4*)(dst + (size_t)(c0 + tr) * R + r0 + tc4) = o;
}

// ---------------- fused scores + softmax -----------------------------------
// One block = (b,h, 16 q-rows). Scores for 16 x SK kept in registers in the
// MFMA C layout (row=4*hh+q, col=r16 within 16-tile). Wave wv owns the
// contiguous column span [wv*SK/4, (wv+1)*SK/4). K fragments gathered direct
// from global (k_bf is L2/L3-resident) using the x32 operand permutation:
// e0..3 = k {4hh..4hh+3}, e4..7 = k {16+4hh..16+4hh+3} per 32-k block.
template <int SK>
__global__ __launch_bounds__(256) void attn_sm(
    const unsigned short* __restrict__ qp, const unsigned short* __restrict__ kp,
    float* __restrict__ w, unsigned short* __restrict__ wb, int Sq,
    float scale) {
  constexpr int TPW = SK / 64;  // 16-col tiles per wave
  const int z = blockIdx.y, b = z >> 3, h = z & 7;
  const int q0 = blockIdx.x * 16;
  const int t = threadIdx.x, wv = t >> 6, lane = t & 63;
  const int hh = lane >> 4, r16 = lane & 15;
  const unsigned short* qrow =
      qp + (size_t)(b * Sq + q0 + r16) * 512 + h * 64 + 4 * hh;
  s16x8 aq[2];
#pragma unroll
  for (int kt = 0; kt < 2; ++kt) {
    ((unsigned long long*)&aq[kt])[0] =
        *(const unsigned long long*)(qrow + kt * 32);
    ((unsigned long long*)&aq[kt])[1] =
        *(const unsigned long long*)(qrow + kt * 32 + 16);
  }
  const unsigned short* kbase = kp + (size_t)b * SK * 512 + h * 64 + 4 * hh;
  f32x4 sc[TPW];
#pragma unroll
  for (int tl = 0; tl < TPW; ++tl) {
    const unsigned short* krow =
        kbase + (size_t)(wv * (TPW * 16) + tl * 16 + r16) * 512;
    s16x8 b0, b1;
    ((unsigned long long*)&b0)[0] = *(const unsigned long long*)(krow);
    ((unsigned long long*)&b0)[1] = *(const unsigned long long*)(krow + 16);
    ((unsigned long long*)&b1)[0] = *(const unsigned long long*)(krow + 32);
    ((unsigned long long*)&b1)[1] = *(const unsigned long long*)(krow + 48);
    f32x4 a = {};
    a = __builtin_amdgcn_mfma_f32_16x16x32_bf16(aq[0], b0, a, 0, 0, 0);
    a = __builtin_amdgcn_mfma_f32_16x16x32_bf16(aq[1], b1, a, 0, 0, 0);
    sc[tl] = a * scale;
  }
  __shared__ float redM[4][16], redS[4][16];
  float mx[4], sm[4];
#pragma unroll
  for (int q = 0; q < 4; ++q) {
    float m = sc[0][q];
#pragma unroll
    for (int tl = 1; tl < TPW; ++tl) m = fmaxf(m, sc[tl][q]);
    mx[q] = m;
  }
#pragma unroll
  for (int off = 1; off < 16; off <<= 1)
#pragma unroll
    for (int q = 0; q < 4; ++q)
      mx[q] = fmaxf(mx[q], __shfl_xor(mx[q], off, 64));
  if (r16 == 0) {
#pragma unroll
    for (int q = 0; q < 4; ++q) redM[wv][hh * 4 + q] = mx[q];
  }
  __syncthreads();
#pragma unroll
  for (int q = 0; q < 4; ++q) {
    const int rr = hh * 4 + q;
    mx[q] = fmaxf(fmaxf(redM[0][rr], redM[1][rr]),
                  fmaxf(redM[2][rr], redM[3][rr]));
    sm[q] = 0.f;
  }
#pragma unroll
  for (int tl = 0; tl < TPW; ++tl)
#pragma unroll
    for (int q = 0; q < 4; ++q) {
      const float e = expf(sc[tl][q] - mx[q]);
      sc[tl][q] = e;
      sm[q] += e;
    }
#pragma unroll
  for (int off = 1; off < 16; off <<= 1)
#pragma unroll
    for (int q = 0; q < 4; ++q) sm[q] += __shfl_xor(sm[q], off, 64);
  if (r16 == 0) {
#pragma unroll
    for (int q = 0; q < 4; ++q) redS[wv][hh * 4 + q] = sm[q];
  }
  __syncthreads();
  float inv[4];
#pragma unroll
  for (int q = 0; q < 4; ++q) {
    const int rr = hh * 4 + q;
    inv[q] = 1.0f / (redS[0][rr] + redS[1][rr] + redS[2][rr] + redS[3][rr]);
  }
  float* wrow = w + ((size_t)z * Sq + q0) * SK;
  unsigned short* wbrow = wb + ((size_t)z * Sq + q0) * SK;
#pragma unroll
  for (int tl = 0; tl < TPW; ++tl) {
    const int col = wv * (TPW * 16) + tl * 16 + r16;
#pragma unroll
    for (int q = 0; q < 4; ++q) {
      const float v = sc[tl][q] * inv[q];
      const size_t o = (size_t)(hh * 4 + q) * SK + col;
      wrow[o] = v;
      wbrow[o] = f2bf(v);
    }
  }
}

// ---------------- MFMA GEMM ------------------------------------------------
// C[m,n] = epi( sum_k A[m,k]*Bt[n,k] + bias[n] )
// A, Bt bf16 row-major. BK=32. LDS rows hold the 32 k-values PERMUTED so that
// one ds_read_b128 at byte h*16 (h = lane>>4) yields the mfma operand
// k = {4h..4h+3, 16+4h..16+4h+3}. Row stride 40 ushorts (80 B).
enum { EPI_B = 0, EPI_BG = 1, EPI_BR = 2, EPI_BGATE = 3, EPI_SC = 4, EPI_KV = 5 };

template <int ROWS>
__device__ __forceinline__ void stage_tile(unsigned short (*lds)[40],
                                           const unsigned short* __restrict__ g,
                                           size_t ld) {
  const int t = threadIdx.x;
  const int jr = t & 3;  // 16B chunk within row: k = 8*jr..8*jr+7
  const int B0 = (jr < 2) ? (jr * 32) : ((jr - 2) * 32 + 8);
#pragma unroll
  for (int p = 0; p < ROWS / 64; ++p) {
    const int row = (t >> 2) + p * 64;
    uint4 u = *(const uint4*)(g + (size_t)row * ld + jr * 8);
    char* dst = (char*)(&lds[row][0]) + B0;
    *(unsigned long long*)dst = ((const unsigned long long*)&u)[0];
    *(unsigned long long*)(dst + 16) = ((const unsigned long long*)&u)[1];
  }
}

template <int EPI, int OM, int BN, bool CONCAT>
__global__ __launch_bounds__(256) void mm(
    const unsigned short* __restrict__ A0,
    const unsigned short* __restrict__ A1, int lda0, int lda1, int K0, int K,
    const unsigned short* __restrict__ Bt, int ldb,
    const float* __restrict__ bias, const float* __restrict__ bias2,
    const float* __restrict__ X1, const float* __restrict__ X2,
    float* __restrict__ outF, unsigned short* __restrict__ outB,
    unsigned short* __restrict__ outT, int ldc, int skShift, float scale,
    size_t aZb, size_t aZh, size_t bZb, size_t bZh, size_t cZb, size_t cZh) {
  constexpr int WN = BN / 2;   // wave n-extent (64 or 32)
  constexpr int NJ = WN / 16;  // n-fragments per wave (4 or 2)
  __shared__ unsigned short As[128][40];
  __shared__ unsigned short Bs[BN][40];
  const int z = blockIdx.z;
  const size_t zb = z >> 3, zh = z & 7;
  const int m0 = blockIdx.y * 128, n0 = blockIdx.x * BN;
  const int t = threadIdx.x;
  const int w = t >> 6, lane = t & 63;
  const int h = lane >> 4, r16 = lane & 15;
  const int wm = w >> 1, wn = w & 1;
  const unsigned short* Ab = A0 + zb * aZb + zh * aZh + (size_t)m0 * lda0;
  const unsigned short* A1b = CONCAT ? (A1 + (size_t)m0 * lda1) : nullptr;
  const unsigned short* Bb = Bt + zb * bZb + zh * bZh + (size_t)n0 * ldb;
  f32x4 acc[4][NJ] = {};
  for (int k0 = 0; k0 < K; k0 += 32) {
    const unsigned short* ag;
    size_t lda;
    if (CONCAT && k0 >= K0) {
      ag = A1b + (k0 - K0);
      lda = (size_t)lda1;
    } else {
      ag = Ab + k0;
      lda = (size_t)lda0;
    }
    stage_tile<128>(As, ag, lda);
    stage_tile<BN>(Bs, Bb + k0, (size_t)ldb);
    __syncthreads();
    const unsigned short* ap = &As[wm * 64 + r16][h * 8];
    const unsigned short* bp = &Bs[wn * WN + r16][h * 8];
    s16x8 av[4], bv[NJ];
#pragma unroll
    for (int i = 0; i < 4; ++i) av[i] = *(const s16x8*)(ap + i * 640);
#pragma unroll
    for (int j = 0; j < NJ; ++j) bv[j] = *(const s16x8*)(bp + j * 640);
#pragma unroll
    for (int i = 0; i < 4; ++i)
#pragma unroll
      for (int j = 0; j < NJ; ++j)
        acc[i][j] = __builtin_amdgcn_mfma_f32_16x16x32_bf16(av[i], bv[j],
                                                            acc[i][j], 0, 0, 0);
    __syncthreads();
  }
  // epilogue: C frag layout col=lane&15, row=4*(lane>>4)+reg  [measured]
  const size_t cz = zb * cZb + zh * cZh;
#pragma unroll
  for (int i = 0; i < 4; ++i) {
    const int rr = m0 + wm * 64 + i * 16 + h * 4;
#pragma unroll
    for (int j = 0; j < NJ; ++j) {
      const int cc = n0 + wn * WN + j * 16 + r16;
      if (EPI == EPI_KV) {
        // K half (cc<512) -> outB[row][cc] bf16; V half -> outT transposed:
        // outT[(b*512 + (cc-512)) * Sk + sk], Sk = 1<<skShift.
        const bool isK = (cc < 512);
        const float bb = isK ? bias[cc] : bias2[cc - 512];
#pragma unroll
        for (int q = 0; q < 4; ++q) {
          const float v = acc[i][j][q] + bb;
          const int r = rr + q;
          if (isK) {
            outB[(size_t)r * 512 + cc] = f2bf(v);
          } else {
            const int b_ = r >> skShift;
            const int sk = r - (b_ << skShift);
            outT[(((size_t)b_ * 512 + (cc - 512)) << skShift) + sk] = f2bf(v);
          }
        }
      } else {
        const float bb = (EPI == EPI_SC) ? 0.f : bias[cc];
#pragma unroll
        for (int q = 0; q < 4; ++q) {
          float v = acc[i][j][q];
          v = (EPI == EPI_SC) ? v * scale : v + bb;
          if (EPI == EPI_BG) v = gelu_exact(v);
          const size_t idx = cz + (size_t)(rr + q) * ldc + cc;
          if (EPI == EPI_BR) v = X1[idx] + v;
          if (EPI == EPI_BGATE) v = X1[idx] + sigmoidf_(v) * X2[idx];
          if (OM & 1) outF[idx] = v;
          if (OM & 2) outB[idx] = f2bf(v);
        }
      }
    }
  }
}

extern "C" void kernel_launch(void* const* d_in, const int* in_sizes, int n_in,
                              void* d_out, int out_size, void* d_ws,
                              size_t ws_size, hipStream_t stream) {
  (void)in_sizes;
  (void)n_in;
  (void)out_size;
  (void)ws_size;
  const int B = 8, Sv = 1024, St = 512, Vd = 1024, Td = 768, E = 512;
  auto inf = [&](int i) { return (const float*)d_in[i]; };
  float* out = (float*)d_out;
  char* ws = (char*)d_ws;
  float* out_vis = out;             // [8192,512]
  float* out_txt = out + 4194304;   // [4096,512]
  float* w_t2v = out + 6291456;     // [8,8,512,1024]
  float* w_v2t = out + 39845888;    // [8,8,1024,512]

  // workspace arena (bytes); ws is ~1120 MiB (harness fill), we use 128 MiB
  const size_t W0 = 0;              // 64 MiB multi-use (w_bf span)
  const size_t R1o = 67108864;      // 16 MiB
  const size_t R2o = 83886080;      // 16 MiB
  const size_t R3o = 100663296;     // weights (<= 8.39 MB)
  const size_t R4o = 109051904;     // vt (<= 8.39 MB)
  const size_t R5o = 117440512;     // q_bf (<= 8.39 MB)
  const size_t R6o = 125829120;     // k_bf (<= 8.39 MB)
  auto U = [&](size_t o) { return (unsigned short*)(ws + o); };
  auto F = [&](size_t o) { return (float*)(ws + o); };

  // ===================== t2v: text queries attend to vision ================
  {
    const int pb = 2;
    const int Sq = St, Sk = Sv, Mq = B * Sq, Mk = B * Sk;  // 512,1024,4096,8192
    unsigned short* wq_t = U(R3o + 0);        // [512][768]
    unsigned short* wk_t = U(R3o + 786432);   // [512][1024]  (wkv rows 0-511)
    unsigned short* wv_t = U(R3o + 1835008);  // [512][1024]  (wkv rows 512-1023)
    unsigned short* wo_t = U(R3o + 2883584);  // [512][512]
    unsigned short* wgp_t = U(R3o + 3407872); // [512][768]
    unsigned short* g1w_t = U(R3o + 4194304); // [512][1024]
    unsigned short* g2w_t = U(R3o + 5242880); // [512][512]
    {
      TP tp{};
      tp.s[0] = inf(pb + 4); tp.d[0] = wq_t;
      tp.s[1] = inf(pb + 12); tp.d[1] = wgp_t;
      tc_kernel<<<dim3(16, 24, 2), 256, 0, stream>>>(tp, 768, 512);
    }
    {
      TP tp{};
      tp.s[0] = inf(pb + 6); tp.d[0] = wk_t;
      tp.s[1] = inf(pb + 8); tp.d[1] = wv_t;
      tp.s[2] = inf(pb + 14); tp.d[2] = g1w_t;
      tc_kernel<<<dim3(16, 32, 3), 256, 0, stream>>>(tp, 1024, 512);
    }
    {
      TP tp{};
      tp.s[0] = inf(pb + 10); tp.d[0] = wo_t;
      tp.s[1] = inf(pb + 18); tp.d[1] = g2w_t;
      tc_kernel<<<dim3(16, 16, 2), 256, 0, stream>>>(tp, 512, 512);
    }
    unsigned short* qn = U(W0);                // [4096,768]
    unsigned short* kn = U(R1o);               // [8192,1024]
    unsigned short* q_bf = U(R5o);             // [4096,512]
    unsigned short* k_bf = U(R6o);             // [8192,512]
    unsigned short* vt = U(R4o);               // [8,512,1024]
    unsigned short* w_bf = U(W0);              // [64,512,1024] = 64 MiB
    unsigned short* ctx_bf = U(R1o);           // [4096,512]
    float* att_f = F(R2o);                     // [4096,512]
    unsigned short* att_bf = U(W0 + 50331648);
    unsigned short* txt_bf = U(W0);            // [4096,768]
    float* qp_f = F(R1o + 8388608);            // [4096,512]
    unsigned short* qp_bf = U(W0 + 58720256);
    float* h_f = F(W0 + 16777216);             // [4096,512]
    unsigned short* hg = U(W0);                // [4096,512]

    ln_kernel<false><<<Mq, 256, 0, stream>>>(inf(1), inf(pb + 0), inf(pb + 1),
                                             qn, Td);
    ln_kernel<false><<<Mk, 256, 0, stream>>>(inf(0), inf(pb + 2), inf(pb + 3),
                                             kn, Vd);
    mm<EPI_B, 2, 64, false><<<dim3(8, 32), 256, 0, stream>>>(
        qn, nullptr, Td, 0, Td, Td, wq_t, Td, inf(pb + 5), nullptr, nullptr,
        nullptr, nullptr, q_bf, nullptr, E, 0, 1.f, 0, 0, 0, 0, 0, 0);
    mm<EPI_KV, 0, 128, false><<<dim3(8, 64), 256, 0, stream>>>(
        kn, nullptr, Vd, 0, Vd, Vd, wk_t, Vd, inf(pb + 7), inf(pb + 9),
        nullptr, nullptr, nullptr, k_bf, vt, 0, 10, 1.f, 0, 0, 0, 0, 0, 0);
    attn_sm<1024><<<dim3(Sq / 16, 64), 256, 0, stream>>>(q_bf, k_bf, w_t2v,
                                                         w_bf, Sq, 0.125f);
    mm<EPI_SC, 2, 64, false><<<dim3(1, Sq / 128, 64), 256, 0, stream>>>(
        w_bf, nullptr, Sk, 0, Sk, Sk, vt, Sk, nullptr, nullptr, nullptr,
        nullptr, nullptr, ctx_bf, nullptr, E, 0, 1.f, (size_t)8 * Sq * Sk,
        (size_t)Sq * Sk, (size_t)E * Sk, (size_t)64 * Sk, (size_t)Sq * E, 64);
    mm<EPI_B, 3, 64, false><<<dim3(8, 32), 256, 0, stream>>>(
        ctx_bf, nullptr, E, 0, E, E, wo_t, E, inf(pb + 11), nullptr, nullptr,
        nullptr, att_f, att_bf, nullptr, E, 0, 1.f, 0, 0, 0, 0, 0, 0);
    cast_kernel<<<1024, 256, 0, stream>>>(inf(1), txt_bf, Mq * Td / 4);
    mm<EPI_B, 3, 64, false><<<dim3(8, 32), 256, 0, stream>>>(
        txt_bf, nullptr, Td, 0, Td, Td, wgp_t, Td, inf(pb + 13), nullptr,
        nullptr, nullptr, qp_f, qp_bf, nullptr, E, 0, 1.f, 0, 0, 0, 0, 0, 0);
    mm<EPI_B, 1, 64, true><<<dim3(8, 32), 256, 0, stream>>>(
        qp_bf, att_bf, E, E, E, 2 * E, g1w_t, 2 * E, inf(pb + 15), nullptr,
        nullptr, nullptr, h_f, nullptr, nullptr, E, 0, 1.f, 0, 0, 0, 0, 0, 0);
    ln_kernel<true><<<Mq, 256, 0, stream>>>(h_f, inf(pb + 16), inf(pb + 17),
                                            hg, E);
    mm<EPI_BGATE, 1, 64, false><<<dim3(8, 32), 256, 0, stream>>>(
        hg, nullptr, E, 0, E, E, g2w_t, E, inf(pb + 19), nullptr, qp_f, att_f,
        out_txt, nullptr, nullptr, E, 0, 1.f, 0, 0, 0, 0, 0, 0);
  }
  // ===================== v2t: vision queries attend to text ================
  {
    const int pb = 22;
    const int Sq = Sv, Sk = St, Mq = B * Sq, Mk = B * St;  // 1024,512,8192,4096
    unsigned short* wq_t = U(R3o + 0);        // [512][1024]
    unsigned short* wk_t = U(R3o + 1048576);  // [512][768]  (wkv rows 0-511)
    unsigned short* wv_t = U(R3o + 1835008);  // [512][768]  (wkv rows 512-1023)
    unsigned short* wo_t = U(R3o + 2621440);  // [512][512]
    unsigned short* wgp_t = U(R3o + 3145728); // [512][1024]
    unsigned short* g1w_t = U(R3o + 4194304); // [512][1024]
    unsigned short* g2w_t = U(R3o + 5242880); // [512][512]
    {
      TP tp{};
      tp.s[0] = inf(pb + 4); tp.d[0] = wq_t;
      tp.s[1] = inf(pb + 12); tp.d[1] = wgp_t;
      tp.s[2] = inf(pb + 14); tp.d[2] = g1w_t;
      tc_kernel<<<dim3(16, 32, 3), 256, 0, stream>>>(tp, 1024, 512);
    }
    {
      TP tp{};
      tp.s[0] = inf(pb + 6); tp.d[0] = wk_t;
      tp.s[1] = inf(pb + 8); tp.d[1] = wv_t;
      tc_kernel<<<dim3(16, 24, 2), 256, 0, stream>>>(tp, 768, 512);
    }
    {
      TP tp{};
      tp.s[0] = inf(pb + 10); tp.d[0] = wo_t;
      tp.s[1] = inf(pb + 18); tp.d[1] = g2w_t;
      tc_kernel<<<dim3(16, 16, 2), 256, 0, stream>>>(tp, 512, 512);
    }
    unsigned short* qn = U(W0);                // [8192,1024]
    unsigned short* kn = U(R1o);               // [4096,768]
    unsigned short* q_bf = U(R5o);             // [8192,512]
    unsigned short* k_bf = U(R6o);             // [4096,512]
    unsigned short* vt = U(R4o);               // [8,512,512]
    unsigned short* w_bf = U(W0);              // [64,1024,512] = 64 MiB
    unsigned short* ctx_bf = U(R1o);           // [8192,512]
    float* att_f = F(R2o);                     // [8192,512]
    unsigned short* att_bf = U(W0 + 50331648);
    unsigned short* vis_bf = U(W0);            // [8192,1024]
    float* qp_f = F(R1o);                      // [8192,512]
    unsigned short* qp_bf = U(W0 + 58720256);
    float* h_f = F(W0 + 16777216);             // [8192,512]
    unsigned short* hg = U(W0);                // [8192,512]

    ln_kernel<false><<<Mq, 256, 0, stream>>>(inf(0), inf(pb + 0), inf(pb + 1),
                                             qn, Vd);
    ln_kernel<false><<<Mk, 256, 0, stream>>>(inf(1), inf(pb + 2), inf(pb + 3),
                                             kn, Td);
    mm<EPI_B, 2, 128, false><<<dim3(4, 64), 256, 0, stream>>>(
        qn, nullptr, Vd, 0, Vd, Vd, wq_t, Vd, inf(pb + 5), nullptr, nullptr,
        nullptr, nullptr, q_bf, nullptr, E, 0, 1.f, 0, 0, 0, 0, 0, 0);
    mm<EPI_KV, 0, 128, false><<<dim3(8, 32), 256, 0, stream>>>(
        kn, nullptr, Td, 0, Td, Td, wk_t, Td, inf(pb + 7), inf(pb + 9),
        nullptr, nullptr, nullptr, k_bf, vt, 0, 9, 1.f, 0, 0, 0, 0, 0, 0);
    attn_sm<512><<<dim3(Sq / 16, 64), 256, 0, stream>>>(q_bf, k_bf, w_v2t,
                                                        w_bf, Sq, 0.125f);
    mm<EPI_SC, 2, 64, false><<<dim3(1, Sq / 128, 64), 256, 0, stream>>>(
        w_bf, nullptr, Sk, 0, Sk, Sk, vt, Sk, nullptr, nullptr, nullptr,
        nullptr, nullptr, ctx_bf, nullptr, E, 0, 1.f, (size_t)8 * Sq * Sk,
        (size_t)Sq * Sk, (size_t)E * Sk, (size_t)64 * Sk, (size_t)Sq * E, 64);
    mm<EPI_B, 3, 128, false><<<dim3(4, 64), 256, 0, stream>>>(
        ctx_bf, nullptr, E, 0, E, E, wo_t, E, inf(pb + 11), nullptr, nullptr,
        nullptr, att_f, att_bf, nullptr, E, 0, 1.f, 0, 0, 0, 0, 0, 0);
    cast_kernel<<<2048, 256, 0, stream>>>(inf(0), vis_bf, Mq * Vd / 4);
    mm<EPI_B, 3, 128, false><<<dim3(4, 64), 256, 0, stream>>>(
        vis_bf, nullptr, Vd, 0, Vd, Vd, wgp_t, Vd, inf(pb + 13), nullptr,
        nullptr, nullptr, qp_f, qp_bf, nullptr, E, 0, 1.f, 0, 0, 0, 0, 0, 0);
    mm<EPI_B, 1, 128, true><<<dim3(4, 64), 256, 0, stream>>>(
        qp_bf, att_bf, E, E, E, 2 * E, g1w_t, 2 * E, inf(pb + 15), nullptr,
        nullptr, nullptr, h_f, nullptr, nullptr, E, 0, 1.f, 0, 0, 0, 0, 0, 0);
    ln_kernel<true><<<Mq, 256, 0, stream>>>(h_f, inf(pb + 16), inf(pb + 17),
                                            hg, E);
    mm<EPI_BGATE, 1, 128, false><<<dim3(4, 64), 256, 0, stream>>>(
        hg, nullptr, E, 0, E, E, g2w_t, E, inf(pb + 19), nullptr, qp_f, att_f,
        out_vis, nullptr, nullptr, E, 0, 1.f, 0, 0, 0, 0, 0, 0);
  }
  // ===================== FF blocks ========================================
  {
    unsigned short* vw1_t = U(R3o + 0);        // [2048][512]
    unsigned short* vw2_t = U(R3o + 2097152);  // [512][2048]
    unsigned short* tw1_t = U(R3o + 4194304);
    unsigned short* tw2_t = U(R3o + 6291456);
    {
      TP tp{};
      tp.s[0] = inf(44); tp.d[0] = vw1_t;
      tp.s[1] = inf(50); tp.d[1] = tw1_t;
      tc_kernel<<<dim3(64, 16, 2), 256, 0, stream>>>(tp, 512, 2048);
    }
    {
      TP tp{};
      tp.s[0] = inf(46); tp.d[0] = vw2_t;
      tp.s[1] = inf(52); tp.d[1] = tw2_t;
      tc_kernel<<<dim3(16, 64, 2), 256, 0, stream>>>(tp, 2048, 512);
    }
    unsigned short* lnv = U(W0);
    unsigned short* y_v = U(W0 + 8388608);   // [8192,2048]
    unsigned short* lnt = U(W0 + 41943040);
    unsigned short* y_t = U(W0 + 46137344);  // [4096,2048]
    ln_kernel<false><<<8192, 256, 0, stream>>>(out_vis, inf(42), inf(43), lnv,
                                               512);
    mm<EPI_BG, 2, 128, false><<<dim3(16, 64), 256, 0, stream>>>(
        lnv, nullptr, 512, 0, 512, 512, vw1_t, 512, inf(45), nullptr, nullptr,
        nullptr, nullptr, y_v, nullptr, 2048, 0, 1.f, 0, 0, 0, 0, 0, 0);
    mm<EPI_BR, 1, 128, false><<<dim3(4, 64), 256, 0, stream>>>(
        y_v, nullptr, 2048, 0, 2048, 2048, vw2_t, 2048, inf(47), nullptr,
        out_vis, nullptr, out_vis, nullptr, nullptr, 512, 0, 1.f, 0, 0, 0, 0,
        0, 0);
    ln_kernel<false><<<4096, 256, 0, stream>>>(out_txt, inf(48), inf(49), lnt,
                                               512);
    mm<EPI_BG, 2, 128, false><<<dim3(16, 32), 256, 0, stream>>>(
        lnt, nullptr, 512, 0, 512, 512, tw1_t, 512, inf(51), nullptr, nullptr,
        nullptr, nullptr, y_t, nullptr, 2048, 0, 1.f, 0, 0, 0, 0, 0, 0);
    mm<EPI_BR, 1, 64, false><<<dim3(8, 32), 256, 0, stream>>>(
        y_t, nullptr, 2048, 0, 2048, 2048, tw2_t, 2048, inf(53), nullptr,
        out_txt, nullptr, out_txt, nullptr, nullptr, 512, 0, 1.f, 0, 0, 0, 0,
        0, 0);
  }
}

// Round 4
// 1108.428 us; speedup vs baseline: 2.5895x; 1.0738x over previous
//
#include <hip/hip_runtime.h>
#include <math.h>

// CoAttentionFusion — bf16 MFMA, fused scores+softmax, fused KV projection.
// B=8, Sv=1024, St=512, Vd=1024, Td=768, E=512, H=8, D=64.
// Round 4: mm rebuilt as 64x64 tile / 4 waves of 32x32 / double-buffered
// single-barrier pipeline with issue-early reg staging (T14). Grids 2-8x
// larger -> 2-8 waves/SIMD instead of 1.

typedef __attribute__((ext_vector_type(8))) short s16x8;     // 8 bf16 (4 VGPR)
typedef __attribute__((ext_vector_type(4))) float f32x4;     // MFMA acc
typedef __attribute__((ext_vector_type(4))) unsigned short us4;

__device__ __forceinline__ float gelu_exact(float x) {
  return 0.5f * x * (1.0f + erff(x * 0.70710678118654752f));
}
__device__ __forceinline__ float sigmoidf_(float x) {
  return 1.0f / (1.0f + expf(-x));
}
__device__ __forceinline__ unsigned short f2bf(float f) {
  unsigned int u = __float_as_uint(f);
  u += 0x7fffu + ((u >> 16) & 1u);  // RNE
  return (unsigned short)(u >> 16);
}

// ---------------- LayerNorm: fp32 in -> bf16 out (optional exact GELU) -----
template <bool GELU>
__global__ __launch_bounds__(256) void ln_kernel(
    const float* __restrict__ x, const float* __restrict__ g,
    const float* __restrict__ b, unsigned short* __restrict__ out, int cols) {
  const int row = blockIdx.x;
  const float2* xr = (const float2*)(x + (size_t)row * cols);
  const float2* g2 = (const float2*)g;
  const float2* b2 = (const float2*)b;
  const int n2 = cols >> 1;
  const int tid = threadIdx.x;
  float s = 0.f, ss = 0.f;
  for (int c = tid; c < n2; c += 256) {
    float2 v = xr[c];
    s += v.x + v.y;
    ss += v.x * v.x + v.y * v.y;
  }
#pragma unroll
  for (int off = 32; off; off >>= 1) {
    s += __shfl_down(s, off, 64);
    ss += __shfl_down(ss, off, 64);
  }
  __shared__ float rs[4], rss[4], stat[2];
  const int lane = tid & 63, wid = tid >> 6;
  if (lane == 0) {
    rs[wid] = s;
    rss[wid] = ss;
  }
  __syncthreads();
  if (tid == 0) {
    float ts = rs[0] + rs[1] + rs[2] + rs[3];
    float tss = rss[0] + rss[1] + rss[2] + rss[3];
    float m = ts / (float)cols;
    float var = tss / (float)cols - m * m;
    stat[0] = m;
    stat[1] = 1.0f / sqrtf(var + 1e-5f);
  }
  __syncthreads();
  const float m = stat[0], inv = stat[1];
  ushort2* o2 = (ushort2*)(out + (size_t)row * cols);
  for (int c = tid; c < n2; c += 256) {
    float2 v = xr[c];
    float2 gg = g2[c], bb = b2[c];
    float o0 = (v.x - m) * inv * gg.x + bb.x;
    float o1 = (v.y - m) * inv * gg.y + bb.y;
    if (GELU) {
      o0 = gelu_exact(o0);
      o1 = gelu_exact(o1);
    }
    ushort2 r;
    r.x = f2bf(o0);
    r.y = f2bf(o1);
    o2[c] = r;
  }
}

// ---------------- flat fp32 -> bf16 cast -----------------------------------
__global__ __launch_bounds__(256) void cast_kernel(
    const float* __restrict__ x, unsigned short* __restrict__ o, int n4) {
  const int stride = gridDim.x * 256;
  for (int i = blockIdx.x * 256 + threadIdx.x; i < n4; i += stride) {
    float4 v = ((const float4*)x)[i];
    us4 r = {f2bf(v.x), f2bf(v.y), f2bf(v.z), f2bf(v.w)};
    ((us4*)o)[i] = r;
  }
}

// ---------------- transpose-cast: fp32 [R,C] -> bf16 [C,R], up to 8 mats ---
struct TP {
  const float* s[8];
  unsigned short* d[8];
};
__global__ __launch_bounds__(256) void tc_kernel(TP tp, int R, int C) {
  __shared__ unsigned short tile[32][33];
  const float* src = tp.s[blockIdx.z];
  unsigned short* dst = tp.d[blockIdx.z];
  const int r0 = blockIdx.y * 32, c0 = blockIdx.x * 32;
  const int t = threadIdx.x;
  const int tr = t >> 3, tc4 = (t & 7) * 4;
  float4 v = *(const float4*)(src + (size_t)(r0 + tr) * C + c0 + tc4);
  tile[tr][tc4 + 0] = f2bf(v.x);
  tile[tr][tc4 + 1] = f2bf(v.y);
  tile[tr][tc4 + 2] = f2bf(v.z);
  tile[tr][tc4 + 3] = f2bf(v.w);
  __syncthreads();
  us4 o = {tile[tc4 + 0][tr], tile[tc4 + 1][tr], tile[tc4 + 2][tr],
           tile[tc4 + 3][tr]};
  *(us4*)(dst + (size_t)(c0 + tr) * R + r0 + tc4) = o;
}

// ---------------- fused scores + softmax -----------------------------------
template <int SK>
__global__ __launch_bounds__(256) void attn_sm(
    const unsigned short* __restrict__ qp, const unsigned short* __restrict__ kp,
    float* __restrict__ w, unsigned short* __restrict__ wb, int Sq,
    float scale) {
  constexpr int TPW = SK / 64;  // 16-col tiles per wave
  const int z = blockIdx.y, b = z >> 3, h = z & 7;
  const int q0 = blockIdx.x * 16;
  const int t = threadIdx.x, wv = t >> 6, lane = t & 63;
  const int hh = lane >> 4, r16 = lane & 15;
  const unsigned short* qrow =
      qp + (size_t)(b * Sq + q0 + r16) * 512 + h * 64 + 4 * hh;
  s16x8 aq[2];
#pragma unroll
  for (int kt = 0; kt < 2; ++kt) {
    ((unsigned long long*)&aq[kt])[0] =
        *(const unsigned long long*)(qrow + kt * 32);
    ((unsigned long long*)&aq[kt])[1] =
        *(const unsigned long long*)(qrow + kt * 32 + 16);
  }
  const unsigned short* kbase = kp + (size_t)b * SK * 512 + h * 64 + 4 * hh;
  f32x4 sc[TPW];
#pragma unroll
  for (int tl = 0; tl < TPW; ++tl) {
    const unsigned short* krow =
        kbase + (size_t)(wv * (TPW * 16) + tl * 16 + r16) * 512;
    s16x8 b0, b1;
    ((unsigned long long*)&b0)[0] = *(const unsigned long long*)(krow);
    ((unsigned long long*)&b0)[1] = *(const unsigned long long*)(krow + 16);
    ((unsigned long long*)&b1)[0] = *(const unsigned long long*)(krow + 32);
    ((unsigned long long*)&b1)[1] = *(const unsigned long long*)(krow + 48);
    f32x4 a = {};
    a = __builtin_amdgcn_mfma_f32_16x16x32_bf16(aq[0], b0, a, 0, 0, 0);
    a = __builtin_amdgcn_mfma_f32_16x16x32_bf16(aq[1], b1, a, 0, 0, 0);
    sc[tl] = a * scale;
  }
  __shared__ float redM[4][16], redS[4][16];
  float mx[4], sm[4];
#pragma unroll
  for (int q = 0; q < 4; ++q) {
    float m = sc[0][q];
#pragma unroll
    for (int tl = 1; tl < TPW; ++tl) m = fmaxf(m, sc[tl][q]);
    mx[q] = m;
  }
#pragma unroll
  for (int off = 1; off < 16; off <<= 1)
#pragma unroll
    for (int q = 0; q < 4; ++q)
      mx[q] = fmaxf(mx[q], __shfl_xor(mx[q], off, 64));
  if (r16 == 0) {
#pragma unroll
    for (int q = 0; q < 4; ++q) redM[wv][hh * 4 + q] = mx[q];
  }
  __syncthreads();
#pragma unroll
  for (int q = 0; q < 4; ++q) {
    const int rr = hh * 4 + q;
    mx[q] = fmaxf(fmaxf(redM[0][rr], redM[1][rr]),
                  fmaxf(redM[2][rr], redM[3][rr]));
    sm[q] = 0.f;
  }
#pragma unroll
  for (int tl = 0; tl < TPW; ++tl)
#pragma unroll
    for (int q = 0; q < 4; ++q) {
      const float e = expf(sc[tl][q] - mx[q]);
      sc[tl][q] = e;
      sm[q] += e;
    }
#pragma unroll
  for (int off = 1; off < 16; off <<= 1)
#pragma unroll
    for (int q = 0; q < 4; ++q) sm[q] += __shfl_xor(sm[q], off, 64);
  if (r16 == 0) {
#pragma unroll
    for (int q = 0; q < 4; ++q) redS[wv][hh * 4 + q] = sm[q];
  }
  __syncthreads();
  float inv[4];
#pragma unroll
  for (int q = 0; q < 4; ++q) {
    const int rr = hh * 4 + q;
    inv[q] = 1.0f / (redS[0][rr] + redS[1][rr] + redS[2][rr] + redS[3][rr]);
  }
  float* wrow = w + ((size_t)z * Sq + q0) * SK;
  unsigned short* wbrow = wb + ((size_t)z * Sq + q0) * SK;
#pragma unroll
  for (int tl = 0; tl < TPW; ++tl) {
    const int col = wv * (TPW * 16) + tl * 16 + r16;
#pragma unroll
    for (int q = 0; q < 4; ++q) {
      const float v = sc[tl][q] * inv[q];
      const size_t o = (size_t)(hh * 4 + q) * SK + col;
      wrow[o] = v;
      wbrow[o] = f2bf(v);
    }
  }
}

// ---------------- MFMA GEMM (64x64 tile, dbuf, single barrier/step) --------
// C[m,n] = epi( sum_k A[m,k]*Bt[n,k] + bias[n] )
// A, Bt bf16 row-major. BK=32. LDS rows hold the 32 k-values PERMUTED so
// one ds_read_b128 at byte h*16 (h=lane>>4) yields operand k =
// {4h..4h+3, 16+4h..16+4h+3}. Row stride 40 ushorts (80 B) -> conflict-free.
// Pipeline per K-step: ds_write(regs staged last step) ; issue next loads ;
// one __syncthreads ; ds_read+MFMA. Double buffer => 1 barrier/step is safe:
// reads of buf c complete before barrier(t); buf c rewritten only at t+2,
// after barrier(t+1).
enum { EPI_B = 0, EPI_BG = 1, EPI_BR = 2, EPI_BGATE = 3, EPI_SC = 4, EPI_KV = 5 };

template <int EPI, int OM, bool CONCAT>
__global__ __launch_bounds__(256) void mm(
    const unsigned short* __restrict__ A0,
    const unsigned short* __restrict__ A1, int lda0, int lda1, int K0, int K,
    const unsigned short* __restrict__ Bt, int ldb,
    const float* __restrict__ bias, const float* __restrict__ bias2,
    const float* __restrict__ X1, const float* __restrict__ X2,
    float* __restrict__ outF, unsigned short* __restrict__ outB,
    unsigned short* __restrict__ outT, int ldc, int skShift, float scale,
    size_t aZb, size_t aZh, size_t bZb, size_t bZh, size_t cZb, size_t cZh) {
  __shared__ unsigned short As[2][64][40];
  __shared__ unsigned short Bs[2][64][40];
  const int z = blockIdx.z;
  const size_t zb = z >> 3, zh = z & 7;
  const int m0 = blockIdx.y * 64, n0 = blockIdx.x * 64;
  const int t = threadIdx.x;
  const int w = t >> 6, lane = t & 63;
  const int h = lane >> 4, r16 = lane & 15;
  const int wm = w >> 1, wn = w & 1;
  const int sr = t >> 2, jr = t & 3;  // staging: row, 16B chunk (k=8*jr..)
  const int B0 = (jr < 2) ? (jr * 32) : ((jr - 2) * 32 + 8);
  const unsigned short* Ab =
      A0 + zb * aZb + zh * aZh + (size_t)(m0 + sr) * lda0 + jr * 8;
  const unsigned short* A1b =
      CONCAT ? (A1 + (size_t)(m0 + sr) * lda1 + jr * 8) : nullptr;
  const unsigned short* Bb =
      Bt + zb * bZb + zh * bZh + (size_t)(n0 + sr) * ldb + jr * 8;
  const int NT = K >> 5;
  auto ldA = [&](int tt) -> uint4 {
    const int k0 = tt * 32;
    if (CONCAT && k0 >= K0) return *(const uint4*)(A1b + (k0 - K0));
    return *(const uint4*)(Ab + k0);
  };
  uint4 ua = ldA(0);
  uint4 ub = *(const uint4*)(Bb);
  f32x4 acc[2][2] = {};
  int cur = 0;
  for (int tt = 0; tt < NT; ++tt) {
    {
      char* da = (char*)&As[cur][sr][0] + B0;
      *(unsigned long long*)da = ((const unsigned long long*)&ua)[0];
      *(unsigned long long*)(da + 16) = ((const unsigned long long*)&ua)[1];
      char* db = (char*)&Bs[cur][sr][0] + B0;
      *(unsigned long long*)db = ((const unsigned long long*)&ub)[0];
      *(unsigned long long*)(db + 16) = ((const unsigned long long*)&ub)[1];
    }
    if (tt + 1 < NT) {
      ua = ldA(tt + 1);
      ub = *(const uint4*)(Bb + (tt + 1) * 32);
    }
    __syncthreads();
    s16x8 av[2], bv[2];
#pragma unroll
    for (int i = 0; i < 2; ++i)
      av[i] = *(const s16x8*)&As[cur][wm * 32 + i * 16 + r16][h * 8];
#pragma unroll
    for (int j = 0; j < 2; ++j)
      bv[j] = *(const s16x8*)&Bs[cur][wn * 32 + j * 16 + r16][h * 8];
#pragma unroll
    for (int i = 0; i < 2; ++i)
#pragma unroll
      for (int j = 0; j < 2; ++j)
        acc[i][j] = __builtin_amdgcn_mfma_f32_16x16x32_bf16(av[i], bv[j],
                                                            acc[i][j], 0, 0, 0);
    cur ^= 1;
  }
  // epilogue: C frag layout col=lane&15, row=4*(lane>>4)+reg  [measured]
  const size_t cz = zb * cZb + zh * cZh;
#pragma unroll
  for (int i = 0; i < 2; ++i) {
    const int rr = m0 + wm * 32 + i * 16 + h * 4;
#pragma unroll
    for (int j = 0; j < 2; ++j) {
      const int cc = n0 + wn * 32 + j * 16 + r16;
      if (EPI == EPI_KV) {
        const bool isK = (cc < 512);
        const float bb = isK ? bias[cc] : bias2[cc - 512];
#pragma unroll
        for (int q = 0; q < 4; ++q) {
          const float v = acc[i][j][q] + bb;
          const int r = rr + q;
          if (isK) {
            outB[(size_t)r * 512 + cc] = f2bf(v);
          } else {
            const int b_ = r >> skShift;
            const int sk = r - (b_ << skShift);
            outT[(((size_t)b_ * 512 + (cc - 512)) << skShift) + sk] = f2bf(v);
          }
        }
      } else {
        const float bb = (EPI == EPI_SC) ? 0.f : bias[cc];
#pragma unroll
        for (int q = 0; q < 4; ++q) {
          float v = acc[i][j][q];
          v = (EPI == EPI_SC) ? v * scale : v + bb;
          if (EPI == EPI_BG) v = gelu_exact(v);
          const size_t idx = cz + (size_t)(rr + q) * ldc + cc;
          if (EPI == EPI_BR) v = X1[idx] + v;
          if (EPI == EPI_BGATE) v = X1[idx] + sigmoidf_(v) * X2[idx];
          if (OM & 1) outF[idx] = v;
          if (OM & 2) outB[idx] = f2bf(v);
        }
      }
    }
  }
}

extern "C" void kernel_launch(void* const* d_in, const int* in_sizes, int n_in,
                              void* d_out, int out_size, void* d_ws,
                              size_t ws_size, hipStream_t stream) {
  (void)in_sizes;
  (void)n_in;
  (void)out_size;
  (void)ws_size;
  const int B = 8, Sv = 1024, St = 512, Vd = 1024, Td = 768, E = 512;
  auto inf = [&](int i) { return (const float*)d_in[i]; };
  float* out = (float*)d_out;
  char* ws = (char*)d_ws;
  float* out_vis = out;             // [8192,512]
  float* out_txt = out + 4194304;   // [4096,512]
  float* w_t2v = out + 6291456;     // [8,8,512,1024]
  float* w_v2t = out + 39845888;    // [8,8,1024,512]

  const size_t W0 = 0;              // 64 MiB multi-use (w_bf span)
  const size_t R1o = 67108864;      // 16 MiB
  const size_t R2o = 83886080;      // 16 MiB
  const size_t R3o = 100663296;     // weights (<= 8.39 MB)
  const size_t R4o = 109051904;     // vt (<= 8.39 MB)
  const size_t R5o = 117440512;     // q_bf (<= 8.39 MB)
  const size_t R6o = 125829120;     // k_bf (<= 8.39 MB)
  auto U = [&](size_t o) { return (unsigned short*)(ws + o); };
  auto F = [&](size_t o) { return (float*)(ws + o); };

  // ===================== t2v: text queries attend to vision ================
  {
    const int pb = 2;
    const int Sq = St, Sk = Sv, Mq = B * Sq, Mk = B * Sk;  // 512,1024,4096,8192
    unsigned short* wq_t = U(R3o + 0);        // [512][768]
    unsigned short* wk_t = U(R3o + 786432);   // [512][1024]
    unsigned short* wv_t = U(R3o + 1835008);  // [512][1024]
    unsigned short* wo_t = U(R3o + 2883584);  // [512][512]
    unsigned short* wgp_t = U(R3o + 3407872); // [512][768]
    unsigned short* g1w_t = U(R3o + 4194304); // [512][1024]
    unsigned short* g2w_t = U(R3o + 5242880); // [512][512]
    {
      TP tp{};
      tp.s[0] = inf(pb + 4); tp.d[0] = wq_t;
      tp.s[1] = inf(pb + 12); tp.d[1] = wgp_t;
      tc_kernel<<<dim3(16, 24, 2), 256, 0, stream>>>(tp, 768, 512);
    }
    {
      TP tp{};
      tp.s[0] = inf(pb + 6); tp.d[0] = wk_t;
      tp.s[1] = inf(pb + 8); tp.d[1] = wv_t;
      tp.s[2] = inf(pb + 14); tp.d[2] = g1w_t;
      tc_kernel<<<dim3(16, 32, 3), 256, 0, stream>>>(tp, 1024, 512);
    }
    {
      TP tp{};
      tp.s[0] = inf(pb + 10); tp.d[0] = wo_t;
      tp.s[1] = inf(pb + 18); tp.d[1] = g2w_t;
      tc_kernel<<<dim3(16, 16, 2), 256, 0, stream>>>(tp, 512, 512);
    }
    unsigned short* qn = U(W0);                // [4096,768]
    unsigned short* kn = U(R1o);               // [8192,1024]
    unsigned short* q_bf = U(R5o);             // [4096,512]
    unsigned short* k_bf = U(R6o);             // [8192,512]
    unsigned short* vt = U(R4o);               // [8,512,1024]
    unsigned short* w_bf = U(W0);              // [64,512,1024] = 64 MiB
    unsigned short* ctx_bf = U(R1o);           // [4096,512]
    float* att_f = F(R2o);                     // [4096,512]
    unsigned short* att_bf = U(W0 + 50331648);
    unsigned short* txt_bf = U(W0);            // [4096,768]
    float* qp_f = F(R1o + 8388608);            // [4096,512]
    unsigned short* qp_bf = U(W0 + 58720256);
    float* h_f = F(W0 + 16777216);             // [4096,512]
    unsigned short* hg = U(W0);                // [4096,512]

    ln_kernel<false><<<Mq, 256, 0, stream>>>(inf(1), inf(pb + 0), inf(pb + 1),
                                             qn, Td);
    ln_kernel<false><<<Mk, 256, 0, stream>>>(inf(0), inf(pb + 2), inf(pb + 3),
                                             kn, Vd);
    mm<EPI_B, 2, false><<<dim3(8, 64), 256, 0, stream>>>(
        qn, nullptr, Td, 0, Td, Td, wq_t, Td, inf(pb + 5), nullptr, nullptr,
        nullptr, nullptr, q_bf, nullptr, E, 0, 1.f, 0, 0, 0, 0, 0, 0);
    mm<EPI_KV, 0, false><<<dim3(16, 128), 256, 0, stream>>>(
        kn, nullptr, Vd, 0, Vd, Vd, wk_t, Vd, inf(pb + 7), inf(pb + 9),
        nullptr, nullptr, nullptr, k_bf, vt, 0, 10, 1.f, 0, 0, 0, 0, 0, 0);
    attn_sm<1024><<<dim3(Sq / 16, 64), 256, 0, stream>>>(q_bf, k_bf, w_t2v,
                                                         w_bf, Sq, 0.125f);
    mm<EPI_SC, 2, false><<<dim3(1, Sq / 64, 64), 256, 0, stream>>>(
        w_bf, nullptr, Sk, 0, Sk, Sk, vt, Sk, nullptr, nullptr, nullptr,
        nullptr, nullptr, ctx_bf, nullptr, E, 0, 1.f, (size_t)8 * Sq * Sk,
        (size_t)Sq * Sk, (size_t)E * Sk, (size_t)64 * Sk, (size_t)Sq * E, 64);
    mm<EPI_B, 3, false><<<dim3(8, 64), 256, 0, stream>>>(
        ctx_bf, nullptr, E, 0, E, E, wo_t, E, inf(pb + 11), nullptr, nullptr,
        nullptr, att_f, att_bf, nullptr, E, 0, 1.f, 0, 0, 0, 0, 0, 0);
    cast_kernel<<<1024, 256, 0, stream>>>(inf(1), txt_bf, Mq * Td / 4);
    mm<EPI_B, 3, false><<<dim3(8, 64), 256, 0, stream>>>(
        txt_bf, nullptr, Td, 0, Td, Td, wgp_t, Td, inf(pb + 13), nullptr,
        nullptr, nullptr, qp_f, qp_bf, nullptr, E, 0, 1.f, 0, 0, 0, 0, 0, 0);
    mm<EPI_B, 1, true><<<dim3(8, 64), 256, 0, stream>>>(
        qp_bf, att_bf, E, E, E, 2 * E, g1w_t, 2 * E, inf(pb + 15), nullptr,
        nullptr, nullptr, h_f, nullptr, nullptr, E, 0, 1.f, 0, 0, 0, 0, 0, 0);
    ln_kernel<true><<<Mq, 256, 0, stream>>>(h_f, inf(pb + 16), inf(pb + 17),
                                            hg, E);
    mm<EPI_BGATE, 1, false><<<dim3(8, 64), 256, 0, stream>>>(
        hg, nullptr, E, 0, E, E, g2w_t, E, inf(pb + 19), nullptr, qp_f, att_f,
        out_txt, nullptr, nullptr, E, 0, 1.f, 0, 0, 0, 0, 0, 0);
  }
  // ===================== v2t: vision queries attend to text ================
  {
    const int pb = 22;
    const int Sq = Sv, Sk = St, Mq = B * Sv, Mk = B * St;  // 1024,512,8192,4096
    unsigned short* wq_t = U(R3o + 0);        // [512][1024]
    unsigned short* wk_t = U(R3o + 1048576);  // [512][768]
    unsigned short* wv_t = U(R3o + 1835008);  // [512][768]
    unsigned short* wo_t = U(R3o + 2621440);  // [512][512]
    unsigned short* wgp_t = U(R3o + 3145728); // [512][1024]
    unsigned short* g1w_t = U(R3o + 4194304); // [512][1024]
    unsigned short* g2w_t = U(R3o + 5242880); // [512][512]
    {
      TP tp{};
      tp.s[0] = inf(pb + 4); tp.d[0] = wq_t;
      tp.s[1] = inf(pb + 12); tp.d[1] = wgp_t;
      tp.s[2] = inf(pb + 14); tp.d[2] = g1w_t;
      tc_kernel<<<dim3(16, 32, 3), 256, 0, stream>>>(tp, 1024, 512);
    }
    {
      TP tp{};
      tp.s[0] = inf(pb + 6); tp.d[0] = wk_t;
      tp.s[1] = inf(pb + 8); tp.d[1] = wv_t;
      tc_kernel<<<dim3(16, 24, 2), 256, 0, stream>>>(tp, 768, 512);
    }
    {
      TP tp{};
      tp.s[0] = inf(pb + 10); tp.d[0] = wo_t;
      tp.s[1] = inf(pb + 18); tp.d[1] = g2w_t;
      tc_kernel<<<dim3(16, 16, 2), 256, 0, stream>>>(tp, 512, 512);
    }
    unsigned short* qn = U(W0);                // [8192,1024]
    unsigned short* kn = U(R1o);               // [4096,768]
    unsigned short* q_bf = U(R5o);             // [8192,512]
    unsigned short* k_bf = U(R6o);             // [4096,512]
    unsigned short* vt = U(R4o);               // [8,512,512]
    unsigned short* w_bf = U(W0);              // [64,1024,512] = 64 MiB
    unsigned short* ctx_bf = U(R1o);           // [8192,512]
    float* att_f = F(R2o);                     // [8192,512]
    unsigned short* att_bf = U(W0 + 50331648);
    unsigned short* vis_bf = U(W0);            // [8192,1024]
    float* qp_f = F(R1o);                      // [8192,512]
    unsigned short* qp_bf = U(W0 + 58720256);
    float* h_f = F(W0 + 16777216);             // [8192,512]
    unsigned short* hg = U(W0);                // [8192,512]

    ln_kernel<false><<<Mq, 256, 0, stream>>>(inf(0), inf(pb + 0), inf(pb + 1),
                                             qn, Vd);
    ln_kernel<false><<<Mk, 256, 0, stream>>>(inf(1), inf(pb + 2), inf(pb + 3),
                                             kn, Td);
    mm<EPI_B, 2, false><<<dim3(8, 128), 256, 0, stream>>>(
        qn, nullptr, Vd, 0, Vd, Vd, wq_t, Vd, inf(pb + 5), nullptr, nullptr,
        nullptr, nullptr, q_bf, nullptr, E, 0, 1.f, 0, 0, 0, 0, 0, 0);
    mm<EPI_KV, 0, false><<<dim3(16, 64), 256, 0, stream>>>(
        kn, nullptr, Td, 0, Td, Td, wk_t, Td, inf(pb + 7), inf(pb + 9),
        nullptr, nullptr, nullptr, k_bf, vt, 0, 9, 1.f, 0, 0, 0, 0, 0, 0);
    attn_sm<512><<<dim3(Sq / 16, 64), 256, 0, stream>>>(q_bf, k_bf, w_v2t,
                                                        w_bf, Sq, 0.125f);
    mm<EPI_SC, 2, false><<<dim3(1, Sq / 64, 64), 256, 0, stream>>>(
        w_bf, nullptr, Sk, 0, Sk, Sk, vt, Sk, nullptr, nullptr, nullptr,
        nullptr, nullptr, ctx_bf, nullptr, E, 0, 1.f, (size_t)8 * Sq * Sk,
        (size_t)Sq * Sk, (size_t)E * Sk, (size_t)64 * Sk, (size_t)Sq * E, 64);
    mm<EPI_B, 3, false><<<dim3(8, 128), 256, 0, stream>>>(
        ctx_bf, nullptr, E, 0, E, E, wo_t, E, inf(pb + 11), nullptr, nullptr,
        nullptr, att_f, att_bf, nullptr, E, 0, 1.f, 0, 0, 0, 0, 0, 0);
    cast_kernel<<<2048, 256, 0, stream>>>(inf(0), vis_bf, Mq * Vd / 4);
    mm<EPI_B, 3, false><<<dim3(8, 128), 256, 0, stream>>>(
        vis_bf, nullptr, Vd, 0, Vd, Vd, wgp_t, Vd, inf(pb + 13), nullptr,
        nullptr, nullptr, qp_f, qp_bf, nullptr, E, 0, 1.f, 0, 0, 0, 0, 0, 0);
    mm<EPI_B, 1, true><<<dim3(8, 128), 256, 0, stream>>>(
        qp_bf, att_bf, E, E, E, 2 * E, g1w_t, 2 * E, inf(pb + 15), nullptr,
        nullptr, nullptr, h_f, nullptr, nullptr, E, 0, 1.f, 0, 0, 0, 0, 0, 0);
    ln_kernel<true><<<Mq, 256, 0, stream>>>(h_f, inf(pb + 16), inf(pb + 17),
                                            hg, E);
    mm<EPI_BGATE, 1, false><<<dim3(8, 128), 256, 0, stream>>>(
        hg, nullptr, E, 0, E, E, g2w_t, E, inf(pb + 19), nullptr, qp_f, att_f,
        out_vis, nullptr, nullptr, E, 0, 1.f, 0, 0, 0, 0, 0, 0);
  }
  // ===================== FF blocks ========================================
  {
    unsigned short* vw1_t = U(R3o + 0);        // [2048][512]
    unsigned short* vw2_t = U(R3o + 2097152);  // [512][2048]
    unsigned short* tw1_t = U(R3o + 4194304);
    unsigned short* tw2_t = U(R3o + 6291456);
    {
      TP tp{};
      tp.s[0] = inf(44); tp.d[0] = vw1_t;
      tp.s[1] = inf(50); tp.d[1] = tw1_t;
      tc_kernel<<<dim3(64, 16, 2), 256, 0, stream>>>(tp, 512, 2048);
    }
    {
      TP tp{};
      tp.s[0] = inf(46); tp.d[0] = vw2_t;
      tp.s[1] = inf(52); tp.d[1] = tw2_t;
      tc_kernel<<<dim3(16, 64, 2), 256, 0, stream>>>(tp, 2048, 512);
    }
    unsigned short* lnv = U(W0);
    unsigned short* y_v = U(W0 + 8388608);   // [8192,2048]
    unsigned short* lnt = U(W0 + 41943040);
    unsigned short* y_t = U(W0 + 46137344);  // [4096,2048]
    ln_kernel<false><<<8192, 256, 0, stream>>>(out_vis, inf(42), inf(43), lnv,
                                               512);
    mm<EPI_BG, 2, false><<<dim3(32, 128), 256, 0, stream>>>(
        lnv, nullptr, 512, 0, 512, 512, vw1_t, 512, inf(45), nullptr, nullptr,
        nullptr, nullptr, y_v, nullptr, 2048, 0, 1.f, 0, 0, 0, 0, 0, 0);
    mm<EPI_BR, 1, false><<<dim3(8, 128), 256, 0, stream>>>(
        y_v, nullptr, 2048, 0, 2048, 2048, vw2_t, 2048, inf(47), nullptr,
        out_vis, nullptr, out_vis, nullptr, nullptr, 512, 0, 1.f, 0, 0, 0, 0,
        0, 0);
    ln_kernel<false><<<4096, 256, 0, stream>>>(out_txt, inf(48), inf(49), lnt,
                                               512);
    mm<EPI_BG, 2, false><<<dim3(32, 64), 256, 0, stream>>>(
        lnt, nullptr, 512, 0, 512, 512, tw1_t, 512, inf(51), nullptr, nullptr,
        nullptr, nullptr, y_t, nullptr, 2048, 0, 1.f, 0, 0, 0, 0, 0, 0);
    mm<EPI_BR, 1, false><<<dim3(8, 64), 256, 0, stream>>>(
        y_t, nullptr, 2048, 0, 2048, 2048, tw2_t, 2048, inf(53), nullptr,
        out_txt, nullptr, out_txt, nullptr, nullptr, 512, 0, 1.f, 0, 0, 0, 0,
        0, 0);
  }
}

// Round 6
// 1096.638 us; speedup vs baseline: 2.6174x; 1.0108x over previous
//
#include <hip/hip_runtime.h>
#include <math.h>

// CoAttentionFusion — bf16 MFMA, merged-dispatch edition.
// B=8, Sv=1024, St=512, Vd=1024, Td=768, E=512, H=8, D=64.
// Round 6 = round 5 resubmit (container failed twice = infra flake, same as
// round 2; full static audit found no OOB/hang — see round-5 analysis).
// 15 dispatches: twin t2v/v2t stages merged per launch; 18 weight transposes
// in one job-table launch; 4 input LNs in one. mm inner loop = round-4
// 64x64 dbuf single-barrier pipeline (verified at 1108 us).

typedef __attribute__((ext_vector_type(8))) short s16x8;     // 8 bf16 (4 VGPR)
typedef __attribute__((ext_vector_type(4))) float f32x4;     // MFMA acc
typedef __attribute__((ext_vector_type(4))) unsigned short us4;

__device__ __forceinline__ float gelu_exact(float x) {
  return 0.5f * x * (1.0f + erff(x * 0.70710678118654752f));
}
__device__ __forceinline__ float sigmoidf_(float x) {
  return 1.0f / (1.0f + expf(-x));
}
__device__ __forceinline__ unsigned short f2bf(float f) {
  unsigned int u = __float_as_uint(f);
  u += 0x7fffu + ((u >> 16) & 1u);  // RNE
  return (unsigned short)(u >> 16);
}

// ---------------- multi-job LayerNorm: fp32 in -> bf16 out (opt GELU) ------
struct LNJ {
  const float* x[4];
  const float* g[4];
  const float* b[4];
  unsigned short* o[4];
  int cols[4];
  int pfx[5];  // row prefix
};
template <bool GELU>
__global__ __launch_bounds__(256) void ln_multi(LNJ p) {
  int row = blockIdx.x, ji = 0;
  while (row >= p.pfx[ji + 1]) ++ji;
  const int lrow = row - p.pfx[ji];
  const int cols = p.cols[ji];
  const float2* xr = (const float2*)(p.x[ji] + (size_t)lrow * cols);
  const float2* g2 = (const float2*)p.g[ji];
  const float2* b2 = (const float2*)p.b[ji];
  const int n2 = cols >> 1;
  const int tid = threadIdx.x;
  float s = 0.f, ss = 0.f;
  for (int c = tid; c < n2; c += 256) {
    float2 v = xr[c];
    s += v.x + v.y;
    ss += v.x * v.x + v.y * v.y;
  }
#pragma unroll
  for (int off = 32; off; off >>= 1) {
    s += __shfl_down(s, off, 64);
    ss += __shfl_down(ss, off, 64);
  }
  __shared__ float rs[4], rss[4], stat[2];
  const int lane = tid & 63, wid = tid >> 6;
  if (lane == 0) {
    rs[wid] = s;
    rss[wid] = ss;
  }
  __syncthreads();
  if (tid == 0) {
    float ts = rs[0] + rs[1] + rs[2] + rs[3];
    float tss = rss[0] + rss[1] + rss[2] + rss[3];
    float m = ts / (float)cols;
    float var = tss / (float)cols - m * m;
    stat[0] = m;
    stat[1] = 1.0f / sqrtf(var + 1e-5f);
  }
  __syncthreads();
  const float m = stat[0], inv = stat[1];
  ushort2* o2 = (ushort2*)(p.o[ji] + (size_t)lrow * cols);
  for (int c = tid; c < n2; c += 256) {
    float2 v = xr[c];
    float2 gg = g2[c], bb = b2[c];
    float o0 = (v.x - m) * inv * gg.x + bb.x;
    float o1 = (v.y - m) * inv * gg.y + bb.y;
    if (GELU) {
      o0 = gelu_exact(o0);
      o1 = gelu_exact(o1);
    }
    ushort2 r;
    r.x = f2bf(o0);
    r.y = f2bf(o1);
    o2[c] = r;
  }
}

// ---------------- dual flat fp32 -> bf16 cast ------------------------------
struct CJ {
  const float* s[2];
  unsigned short* d[2];
  int n4[2];
};
__global__ __launch_bounds__(256) void cast2(CJ p) {
  const int z = blockIdx.z;
  const float* x = p.s[z];
  unsigned short* o = p.d[z];
  const int n4 = p.n4[z];
  const int stride = gridDim.x * 256;
  for (int i = blockIdx.x * 256 + threadIdx.x; i < n4; i += stride) {
    float4 v = ((const float4*)x)[i];
    us4 r = {f2bf(v.x), f2bf(v.y), f2bf(v.z), f2bf(v.w)};
    ((us4*)o)[i] = r;
  }
}

// ---------------- transpose-cast job table: 18 mats, one launch ------------
struct TCJ {
  const float* s[18];
  unsigned int doff[18];     // byte offset into wt base
  unsigned short cy[18], cx[18];  // R/32, C/32
  unsigned short pfx[19];    // tile prefix
};
__global__ __launch_bounds__(256) void tc_all(TCJ p, unsigned short* wt) {
  __shared__ unsigned short tile[32][33];
  int t = blockIdx.x, ji = 0;
  while (t >= p.pfx[ji + 1]) ++ji;
  const int lt = t - p.pfx[ji];
  const int cx = p.cx[ji];
  const int ty = lt / cx, tx = lt - ty * cx;
  const int R = p.cy[ji] * 32, C = cx * 32;
  const float* src = p.s[ji];
  unsigned short* dst = (unsigned short*)((char*)wt + p.doff[ji]);
  const int r0 = ty * 32, c0 = tx * 32;
  const int tid = threadIdx.x;
  const int tr = tid >> 3, tc4 = (tid & 7) * 4;
  float4 v = *(const float4*)(src + (size_t)(r0 + tr) * C + c0 + tc4);
  tile[tr][tc4 + 0] = f2bf(v.x);
  tile[tr][tc4 + 1] = f2bf(v.y);
  tile[tr][tc4 + 2] = f2bf(v.z);
  tile[tr][tc4 + 3] = f2bf(v.w);
  __syncthreads();
  us4 o = {tile[tc4 + 0][tr], tile[tc4 + 1][tr], tile[tc4 + 2][tr],
           tile[tc4 + 3][tr]};
  *(us4*)(dst + (size_t)(c0 + tr) * R + r0 + tc4) = o;
}

// ---------------- fused scores + softmax (both sides, one launch) ----------
template <int SK>
__device__ __forceinline__ void attn_body(
    const unsigned short* __restrict__ qp, const unsigned short* __restrict__ kp,
    float* __restrict__ w, unsigned short* __restrict__ wb, int Sq, int z,
    int qblk) {
  constexpr int TPW = SK / 64;
  const int b = z >> 3, h = z & 7;
  const int q0 = qblk * 16;
  const int t = threadIdx.x, wv = t >> 6, lane = t & 63;
  const int hh = lane >> 4, r16 = lane & 15;
  const unsigned short* qrow =
      qp + (size_t)(b * Sq + q0 + r16) * 512 + h * 64 + 4 * hh;
  s16x8 aq[2];
#pragma unroll
  for (int kt = 0; kt < 2; ++kt) {
    ((unsigned long long*)&aq[kt])[0] =
        *(const unsigned long long*)(qrow + kt * 32);
    ((unsigned long long*)&aq[kt])[1] =
        *(const unsigned long long*)(qrow + kt * 32 + 16);
  }
  const unsigned short* kbase = kp + (size_t)b * SK * 512 + h * 64 + 4 * hh;
  f32x4 sc[TPW];
#pragma unroll
  for (int tl = 0; tl < TPW; ++tl) {
    const unsigned short* krow =
        kbase + (size_t)(wv * (TPW * 16) + tl * 16 + r16) * 512;
    s16x8 b0, b1;
    ((unsigned long long*)&b0)[0] = *(const unsigned long long*)(krow);
    ((unsigned long long*)&b0)[1] = *(const unsigned long long*)(krow + 16);
    ((unsigned long long*)&b1)[0] = *(const unsigned long long*)(krow + 32);
    ((unsigned long long*)&b1)[1] = *(const unsigned long long*)(krow + 48);
    f32x4 a = {};
    a = __builtin_amdgcn_mfma_f32_16x16x32_bf16(aq[0], b0, a, 0, 0, 0);
    a = __builtin_amdgcn_mfma_f32_16x16x32_bf16(aq[1], b1, a, 0, 0, 0);
    sc[tl] = a * 0.125f;
  }
  __shared__ float redM[4][16], redS[4][16];
  float mx[4], sm[4];
#pragma unroll
  for (int q = 0; q < 4; ++q) {
    float m = sc[0][q];
#pragma unroll
    for (int tl = 1; tl < TPW; ++tl) m = fmaxf(m, sc[tl][q]);
    mx[q] = m;
  }
#pragma unroll
  for (int off = 1; off < 16; off <<= 1)
#pragma unroll
    for (int q = 0; q < 4; ++q)
      mx[q] = fmaxf(mx[q], __shfl_xor(mx[q], off, 64));
  if (r16 == 0) {
#pragma unroll
    for (int q = 0; q < 4; ++q) redM[wv][hh * 4 + q] = mx[q];
  }
  __syncthreads();
#pragma unroll
  for (int q = 0; q < 4; ++q) {
    const int rr = hh * 4 + q;
    mx[q] = fmaxf(fmaxf(redM[0][rr], redM[1][rr]),
                  fmaxf(redM[2][rr], redM[3][rr]));
    sm[q] = 0.f;
  }
#pragma unroll
  for (int tl = 0; tl < TPW; ++tl)
#pragma unroll
    for (int q = 0; q < 4; ++q) {
      const float e = expf(sc[tl][q] - mx[q]);
      sc[tl][q] = e;
      sm[q] += e;
    }
#pragma unroll
  for (int off = 1; off < 16; off <<= 1)
#pragma unroll
    for (int q = 0; q < 4; ++q) sm[q] += __shfl_xor(sm[q], off, 64);
  if (r16 == 0) {
#pragma unroll
    for (int q = 0; q < 4; ++q) redS[wv][hh * 4 + q] = sm[q];
  }
  __syncthreads();
  float inv[4];
#pragma unroll
  for (int q = 0; q < 4; ++q) {
    const int rr = hh * 4 + q;
    inv[q] = 1.0f / (redS[0][rr] + redS[1][rr] + redS[2][rr] + redS[3][rr]);
  }
  float* wrow = w + ((size_t)z * Sq + q0) * SK;
  unsigned short* wbrow = wb + ((size_t)z * Sq + q0) * SK;
#pragma unroll
  for (int tl = 0; tl < TPW; ++tl) {
    const int col = wv * (TPW * 16) + tl * 16 + r16;
#pragma unroll
    for (int q = 0; q < 4; ++q) {
      const float v = sc[tl][q] * inv[q];
      const size_t o = (size_t)(hh * 4 + q) * SK + col;
      wrow[o] = v;
      wbrow[o] = f2bf(v);
    }
  }
}

__global__ __launch_bounds__(256) void attn2(
    const unsigned short* q0, const unsigned short* k0, float* w0,
    unsigned short* wb0, const unsigned short* q1, const unsigned short* k1,
    float* w1, unsigned short* wb1) {
  const int y = blockIdx.y;
  if (y < 64) {
    if (blockIdx.x >= 32) return;  // side0: Sq=512 -> 32 q-blocks
    attn_body<1024>(q0, k0, w0, wb0, 512, y, blockIdx.x);
  } else {
    attn_body<512>(q1, k1, w1, wb1, 1024, y - 64, blockIdx.x);
  }
}

// ---------------- MFMA GEMM (64x64, dbuf, 1 barrier/step) — 2-job merged ---
enum { EPI_B = 0, EPI_BG = 1, EPI_BR = 2, EPI_BGATE = 3, EPI_SC = 4, EPI_KV = 5 };

struct MMJ {
  const unsigned short *A0, *A1, *Bt;
  const float *bias, *bias2, *X1, *X2;
  float* outF;
  unsigned short *outB, *outT;
  int lda0, lda1, K0, K, ldb, ldc, skShift, ny, nz;
  float scale;
  size_t aZb, aZh, bZb, bZh, cZb, cZh;
};

template <int EPI, int OM, bool CONCAT, bool ZSPLIT>
__global__ __launch_bounds__(256) void mm2(MMJ j0, MMJ j1) {
  int y = blockIdx.y, z = blockIdx.z;
  bool side;
  if (ZSPLIT) {
    side = (z >= j0.nz);
    if (side) z -= j0.nz;
    if (y >= (side ? j1.ny : j0.ny)) return;
  } else {
    side = (y >= j0.ny);
    if (side) y -= j0.ny;
  }
  const MMJ& j = side ? j1 : j0;
  __shared__ unsigned short As[2][64][40];
  __shared__ unsigned short Bs[2][64][40];
  const size_t zb = z >> 3, zh = z & 7;
  const int m0 = y * 64, n0 = blockIdx.x * 64;
  const int t = threadIdx.x;
  const int w = t >> 6, lane = t & 63;
  const int h = lane >> 4, r16 = lane & 15;
  const int wm = w >> 1, wn = w & 1;
  const int sr = t >> 2, jr = t & 3;
  const int B0 = (jr < 2) ? (jr * 32) : ((jr - 2) * 32 + 8);
  const unsigned short* Ab =
      j.A0 + zb * j.aZb + zh * j.aZh + (size_t)(m0 + sr) * j.lda0 + jr * 8;
  const unsigned short* A1b =
      CONCAT ? (j.A1 + (size_t)(m0 + sr) * j.lda1 + jr * 8) : nullptr;
  const unsigned short* Bb =
      j.Bt + zb * j.bZb + zh * j.bZh + (size_t)(n0 + sr) * j.ldb + jr * 8;
  const int NT = j.K >> 5;
  auto ldA = [&](int tt) -> uint4 {
    const int k0 = tt * 32;
    if (CONCAT && k0 >= j.K0) return *(const uint4*)(A1b + (k0 - j.K0));
    return *(const uint4*)(Ab + k0);
  };
  uint4 ua = ldA(0);
  uint4 ub = *(const uint4*)(Bb);
  f32x4 acc[2][2] = {};
  int cur = 0;
  for (int tt = 0; tt < NT; ++tt) {
    {
      char* da = (char*)&As[cur][sr][0] + B0;
      *(unsigned long long*)da = ((const unsigned long long*)&ua)[0];
      *(unsigned long long*)(da + 16) = ((const unsigned long long*)&ua)[1];
      char* db = (char*)&Bs[cur][sr][0] + B0;
      *(unsigned long long*)db = ((const unsigned long long*)&ub)[0];
      *(unsigned long long*)(db + 16) = ((const unsigned long long*)&ub)[1];
    }
    if (tt + 1 < NT) {
      ua = ldA(tt + 1);
      ub = *(const uint4*)(Bb + (tt + 1) * 32);
    }
    __syncthreads();
    s16x8 av[2], bv[2];
#pragma unroll
    for (int i = 0; i < 2; ++i)
      av[i] = *(const s16x8*)&As[cur][wm * 32 + i * 16 + r16][h * 8];
#pragma unroll
    for (int jx = 0; jx < 2; ++jx)
      bv[jx] = *(const s16x8*)&Bs[cur][wn * 32 + jx * 16 + r16][h * 8];
#pragma unroll
    for (int i = 0; i < 2; ++i)
#pragma unroll
      for (int jx = 0; jx < 2; ++jx)
        acc[i][jx] = __builtin_amdgcn_mfma_f32_16x16x32_bf16(av[i], bv[jx],
                                                             acc[i][jx], 0, 0, 0);
    cur ^= 1;
  }
  const size_t cz = zb * j.cZb + zh * j.cZh;
#pragma unroll
  for (int i = 0; i < 2; ++i) {
    const int rr = m0 + wm * 32 + i * 16 + h * 4;
#pragma unroll
    for (int jx = 0; jx < 2; ++jx) {
      const int cc = n0 + wn * 32 + jx * 16 + r16;
      if (EPI == EPI_KV) {
        const bool isK = (cc < 512);
        const float bb = isK ? j.bias[cc] : j.bias2[cc - 512];
#pragma unroll
        for (int q = 0; q < 4; ++q) {
          const float v = acc[i][jx][q] + bb;
          const int r = rr + q;
          if (isK) {
            j.outB[(size_t)r * 512 + cc] = f2bf(v);
          } else {
            const int b_ = r >> j.skShift;
            const int sk = r - (b_ << j.skShift);
            j.outT[(((size_t)b_ * 512 + (cc - 512)) << j.skShift) + sk] =
                f2bf(v);
          }
        }
      } else {
        const float bb = (EPI == EPI_SC) ? 0.f : j.bias[cc];
#pragma unroll
        for (int q = 0; q < 4; ++q) {
          float v = acc[i][jx][q];
          v = (EPI == EPI_SC) ? v * j.scale : v + bb;
          if (EPI == EPI_BG) v = gelu_exact(v);
          const size_t idx = cz + (size_t)(rr + q) * j.ldc + cc;
          if (EPI == EPI_BR) v = j.X1[idx] + v;
          if (EPI == EPI_BGATE) v = j.X1[idx] + sigmoidf_(v) * j.X2[idx];
          if (OM & 1) j.outF[idx] = v;
          if (OM & 2) j.outB[idx] = f2bf(v);
        }
      }
    }
  }
}

extern "C" void kernel_launch(void* const* d_in, const int* in_sizes, int n_in,
                              void* d_out, int out_size, void* d_ws,
                              size_t ws_size, hipStream_t stream) {
  (void)in_sizes;
  (void)n_in;
  (void)out_size;
  (void)ws_size;
  auto inf = [&](int i) { return (const float*)d_in[i]; };
  float* out = (float*)d_out;
  char* ws = (char*)d_ws;
  float* out_vis = out;             // [8192,512]
  float* out_txt = out + 4194304;   // [4096,512]
  float* w_t2v = out + 6291456;     // [8,8,512,1024]
  float* w_v2t = out + 39845888;    // [8,8,1024,512]

  const size_t MBy = 1048576;
  auto U = [&](size_t mb) { return (unsigned short*)(ws + mb * MBy); };
  auto F = [&](size_t mb) { return (float*)(ws + mb * MBy); };
  unsigned short* wt = U(0);  // 20 MB: t2v@0, v2t@6291456, ff@12582912
  const size_t T2V = 0, V2T = 6291456, FFW = 12582912;
  unsigned short* qn0 = U(20);   // [4096,768]
  unsigned short* kn0 = U(26);   // [8192,1024]
  unsigned short* qn1 = U(42);   // [8192,1024]
  unsigned short* kn1 = U(58);   // [4096,768]
  unsigned short* txt_bf = U(64);
  unsigned short* vis_bf = U(70);
  unsigned short* q_bf0 = U(86);
  unsigned short* q_bf1 = U(90);
  unsigned short* k_bf0 = U(98);
  unsigned short* k_bf1 = U(106);
  unsigned short* vt0 = U(110);  // [8,512,1024]
  unsigned short* vt1 = U(118);  // [8,512,512]
  unsigned short* w_bf0 = U(122);  // 64 MB
  unsigned short* w_bf1 = U(186);  // 64 MB
  unsigned short* ctx0 = U(250);
  unsigned short* ctx1 = U(254);
  float* att_f0 = F(262);
  unsigned short* att_bf0 = U(270);
  float* att_f1 = F(274);
  unsigned short* att_bf1 = U(290);
  float* qp_f0 = F(298);
  unsigned short* qp_bf0 = U(306);
  float* qp_f1 = F(310);
  unsigned short* qp_bf1 = U(326);
  float* h_f0 = F(334);
  float* h_f1 = F(342);
  unsigned short* hg0 = U(358);
  unsigned short* hg1 = U(362);
  unsigned short* lnv = U(370);
  unsigned short* lnt = U(378);
  unsigned short* y_v = U(382);  // [8192,2048]
  unsigned short* y_t = U(414);  // [4096,2048]

  auto mkj = []() { MMJ j{}; j.scale = 1.f; j.nz = 1; return j; };

  // ---- 1. all weight transposes ----
  {
    TCJ p{};
    const int srcIdx[18] = {6, 8, 10, 12, 14, 16, 20, 26, 28, 30, 32, 34,
                            36, 40, 44, 46, 50, 52};
    const unsigned int doff[18] = {
        T2V + 0, T2V + 786432, T2V + 1835008, T2V + 2883584, T2V + 3407872,
        T2V + 4194304, T2V + 5242880, V2T + 0, V2T + 1048576, V2T + 1835008,
        V2T + 2621440, V2T + 3145728, V2T + 4194304, V2T + 5242880,
        FFW + 0, FFW + 2097152, FFW + 4194304, FFW + 6291456};
    const unsigned short cy[18] = {24, 32, 32, 16, 24, 32, 16, 32, 24, 24,
                                   16, 32, 32, 16, 16, 64, 16, 64};
    const unsigned short cx[18] = {16, 16, 16, 16, 16, 16, 16, 16, 16, 16,
                                   16, 16, 16, 16, 64, 16, 64, 16};
    unsigned short acc = 0;
    for (int i = 0; i < 18; ++i) {
      p.s[i] = inf(srcIdx[i]);
      p.doff[i] = doff[i];
      p.cy[i] = cy[i];
      p.cx[i] = cx[i];
      p.pfx[i] = acc;
      acc += cy[i] * cx[i];
    }
    p.pfx[18] = acc;  // 9728
    tc_all<<<acc, 256, 0, stream>>>(p, wt);
  }
  // ---- 2. four input LNs ----
  {
    LNJ p{};
    p.x[0] = inf(1); p.g[0] = inf(2); p.b[0] = inf(3); p.o[0] = qn0; p.cols[0] = 768;
    p.x[1] = inf(0); p.g[1] = inf(4); p.b[1] = inf(5); p.o[1] = kn0; p.cols[1] = 1024;
    p.x[2] = inf(0); p.g[2] = inf(22); p.b[2] = inf(23); p.o[2] = qn1; p.cols[2] = 1024;
    p.x[3] = inf(1); p.g[3] = inf(24); p.b[3] = inf(25); p.o[3] = kn1; p.cols[3] = 768;
    p.pfx[0] = 0; p.pfx[1] = 4096; p.pfx[2] = 12288; p.pfx[3] = 20480; p.pfx[4] = 24576;
    ln_multi<false><<<24576, 256, 0, stream>>>(p);
  }
  // ---- 3. raw-input casts ----
  {
    CJ p{};
    p.s[0] = inf(1); p.d[0] = txt_bf; p.n4[0] = 4096 * 768 / 4;
    p.s[1] = inf(0); p.d[1] = vis_bf; p.n4[1] = 8192 * 1024 / 4;
    cast2<<<dim3(2048, 1, 2), 256, 0, stream>>>(p);
  }
  // ---- 4. Q projections ----
  {
    MMJ a = mkj(), b = mkj();
    a.A0 = qn0; a.lda0 = 768; a.K = 768; a.Bt = wt + T2V / 2; a.ldb = 768;
    a.bias = inf(7); a.outB = q_bf0; a.ldc = 512; a.ny = 64;
    b.A0 = qn1; b.lda0 = 1024; b.K = 1024; b.Bt = wt + V2T / 2; b.ldb = 1024;
    b.bias = inf(27); b.outB = q_bf1; b.ldc = 512; b.ny = 128;
    mm2<EPI_B, 2, false, false><<<dim3(8, 192), 256, 0, stream>>>(a, b);
  }
  // ---- 5. fused KV projections ----
  {
    MMJ a = mkj(), b = mkj();
    a.A0 = kn0; a.lda0 = 1024; a.K = 1024;
    a.Bt = wt + (T2V + 786432) / 2; a.ldb = 1024;
    a.bias = inf(9); a.bias2 = inf(11); a.outB = k_bf0; a.outT = vt0;
    a.skShift = 10; a.ny = 128;
    b.A0 = kn1; b.lda0 = 768; b.K = 768;
    b.Bt = wt + (V2T + 1048576) / 2; b.ldb = 768;
    b.bias = inf(29); b.bias2 = inf(31); b.outB = k_bf1; b.outT = vt1;
    b.skShift = 9; b.ny = 64;
    mm2<EPI_KV, 0, false, false><<<dim3(16, 192), 256, 0, stream>>>(a, b);
  }
  // ---- 6. scores + softmax (both sides) ----
  attn2<<<dim3(64, 128), 256, 0, stream>>>(q_bf0, k_bf0, w_t2v, w_bf0, q_bf1,
                                           k_bf1, w_v2t, w_bf1);
  // ---- 7. ctx = P @ V ----
  {
    MMJ a = mkj(), b = mkj();
    a.A0 = w_bf0; a.lda0 = 1024; a.K = 1024; a.Bt = vt0; a.ldb = 1024;
    a.outB = ctx0; a.ldc = 512; a.ny = 8; a.nz = 64;
    a.aZb = (size_t)8 * 512 * 1024; a.aZh = 512 * 1024;
    a.bZb = 512 * 1024; a.bZh = 64 * 1024;
    a.cZb = 512 * 512; a.cZh = 64;
    b.A0 = w_bf1; b.lda0 = 512; b.K = 512; b.Bt = vt1; b.ldb = 512;
    b.outB = ctx1; b.ldc = 512; b.ny = 16; b.nz = 64;
    b.aZb = (size_t)8 * 1024 * 512; b.aZh = 1024 * 512;
    b.bZb = 512 * 512; b.bZh = 64 * 512;
    b.cZb = 1024 * 512; b.cZh = 64;
    mm2<EPI_SC, 2, false, true><<<dim3(1, 16, 128), 256, 0, stream>>>(a, b);
  }
  // ---- 8. attention output projection ----
  {
    MMJ a = mkj(), b = mkj();
    a.A0 = ctx0; a.lda0 = 512; a.K = 512;
    a.Bt = wt + (T2V + 2883584) / 2; a.ldb = 512;
    a.bias = inf(13); a.outF = att_f0; a.outB = att_bf0; a.ldc = 512; a.ny = 64;
    b.A0 = ctx1; b.lda0 = 512; b.K = 512;
    b.Bt = wt + (V2T + 2621440) / 2; b.ldb = 512;
    b.bias = inf(33); b.outF = att_f1; b.outB = att_bf1; b.ldc = 512;
    b.ny = 128;
    mm2<EPI_B, 3, false, false><<<dim3(8, 192), 256, 0, stream>>>(a, b);
  }
  // ---- 9. query-gate projections ----
  {
    MMJ a = mkj(), b = mkj();
    a.A0 = txt_bf; a.lda0 = 768; a.K = 768;
    a.Bt = wt + (T2V + 3407872) / 2; a.ldb = 768;
    a.bias = inf(15); a.outF = qp_f0; a.outB = qp_bf0; a.ldc = 512; a.ny = 64;
    b.A0 = vis_bf; b.lda0 = 1024; b.K = 1024;
    b.Bt = wt + (V2T + 3145728) / 2; b.ldb = 1024;
    b.bias = inf(35); b.outF = qp_f1; b.outB = qp_bf1; b.ldc = 512; b.ny = 128;
    mm2<EPI_B, 3, false, false><<<dim3(8, 192), 256, 0, stream>>>(a, b);
  }
  // ---- 10. g1: [qp|att] @ g1w ----
  {
    MMJ a = mkj(), b = mkj();
    a.A0 = qp_bf0; a.A1 = att_bf0; a.lda0 = 512; a.lda1 = 512; a.K0 = 512;
    a.K = 1024; a.Bt = wt + (T2V + 4194304) / 2; a.ldb = 1024;
    a.bias = inf(17); a.outF = h_f0; a.ldc = 512; a.ny = 64;
    b.A0 = qp_bf1; b.A1 = att_bf1; b.lda0 = 512; b.lda1 = 512; b.K0 = 512;
    b.K = 1024; b.Bt = wt + (V2T + 4194304) / 2; b.ldb = 1024;
    b.bias = inf(37); b.outF = h_f1; b.ldc = 512; b.ny = 128;
    mm2<EPI_B, 1, true, false><<<dim3(8, 192), 256, 0, stream>>>(a, b);
  }
  // ---- 11. gate LN + GELU ----
  {
    LNJ p{};
    p.x[0] = h_f0; p.g[0] = inf(18); p.b[0] = inf(19); p.o[0] = hg0; p.cols[0] = 512;
    p.x[1] = h_f1; p.g[1] = inf(38); p.b[1] = inf(39); p.o[1] = hg1; p.cols[1] = 512;
    p.x[2] = h_f0; p.g[2] = inf(18); p.b[2] = inf(19); p.o[2] = hg0; p.cols[2] = 512;
    p.x[3] = p.x[2]; p.g[3] = p.g[2]; p.b[3] = p.b[2]; p.o[3] = p.o[2]; p.cols[3] = 512;
    p.pfx[0] = 0; p.pfx[1] = 4096; p.pfx[2] = 12288; p.pfx[3] = 12288; p.pfx[4] = 12288;
    ln_multi<true><<<12288, 256, 0, stream>>>(p);
  }
  // ---- 12. gated combine ----
  {
    MMJ a = mkj(), b = mkj();
    a.A0 = hg0; a.lda0 = 512; a.K = 512;
    a.Bt = wt + (T2V + 5242880) / 2; a.ldb = 512;
    a.bias = inf(21); a.X1 = qp_f0; a.X2 = att_f0; a.outF = out_txt;
    a.ldc = 512; a.ny = 64;
    b.A0 = hg1; b.lda0 = 512; b.K = 512;
    b.Bt = wt + (V2T + 5242880) / 2; b.ldb = 512;
    b.bias = inf(41); b.X1 = qp_f1; b.X2 = att_f1; b.outF = out_vis;
    b.ldc = 512; b.ny = 128;
    mm2<EPI_BGATE, 1, false, false><<<dim3(8, 192), 256, 0, stream>>>(a, b);
  }
  // ---- 13. FF LNs ----
  {
    LNJ p{};
    p.x[0] = out_vis; p.g[0] = inf(42); p.b[0] = inf(43); p.o[0] = lnv; p.cols[0] = 512;
    p.x[1] = out_txt; p.g[1] = inf(48); p.b[1] = inf(49); p.o[1] = lnt; p.cols[1] = 512;
    p.x[2] = out_vis; p.g[2] = inf(42); p.b[2] = inf(43); p.o[2] = lnv; p.cols[2] = 512;
    p.x[3] = p.x[2]; p.g[3] = p.g[2]; p.b[3] = p.b[2]; p.o[3] = p.o[2]; p.cols[3] = 512;
    p.pfx[0] = 0; p.pfx[1] = 8192; p.pfx[2] = 12288; p.pfx[3] = 12288; p.pfx[4] = 12288;
    ln_multi<false><<<12288, 256, 0, stream>>>(p);
  }
  // ---- 14. FF1 (+GELU) ----
  {
    MMJ a = mkj(), b = mkj();
    a.A0 = lnv; a.lda0 = 512; a.K = 512; a.Bt = wt + FFW / 2; a.ldb = 512;
    a.bias = inf(45); a.outB = y_v; a.ldc = 2048; a.ny = 128;
    b.A0 = lnt; b.lda0 = 512; b.K = 512;
    b.Bt = wt + (FFW + 4194304) / 2; b.ldb = 512;
    b.bias = inf(51); b.outB = y_t; b.ldc = 2048; b.ny = 64;
    mm2<EPI_BG, 2, false, false><<<dim3(32, 192), 256, 0, stream>>>(a, b);
  }
  // ---- 15. FF2 (+residual) ----
  {
    MMJ a = mkj(), b = mkj();
    a.A0 = y_v; a.lda0 = 2048; a.K = 2048;
    a.Bt = wt + (FFW + 2097152) / 2; a.ldb = 2048;
    a.bias = inf(47); a.X1 = out_vis; a.outF = out_vis; a.ldc = 512; a.ny = 128;
    b.A0 = y_t; b.lda0 = 2048; b.K = 2048;
    b.Bt = wt + (FFW + 6291456) / 2; b.ldb = 2048;
    b.bias = inf(53); b.X1 = out_txt; b.outF = out_txt; b.ldc = 512; b.ny = 64;
    mm2<EPI_BR, 1, false, false><<<dim3(8, 192), 256, 0, stream>>>(a, b);
  }
}